// Round 8
// baseline (471.879 us; speedup 1.0000x reference)
//
#include <hip/hip_runtime.h>
#include <hip/hip_cooperative_groups.h>
#include <math.h>

namespace cg = cooperative_groups;

#define CC 96
#define NP 4096
#define NHEADS 6
#define NELEMF 393216.0f
#define EPSF 1e-5f

typedef __attribute__((ext_vector_type(8))) short bf16x8;
typedef __attribute__((ext_vector_type(4))) float f32x4;
#define MFMA16(a,b,c) __builtin_amdgcn_mfma_f32_16x16x32_bf16(a,b,c,0,0,0)

// ---- workspace layout (float offsets) ----
#define WQKV1  64
#define WQKV2  (WQKV1+13824)
#define WPROJ1 (WQKV2+13824)
#define WPROJ2 (WPROJ1+4608)
#define WMLP1  (WPROJ2+4608)
#define WMLP2  (WMLP1+18432)
#define WM2A1  (WMLP2+18432)
#define WM2A2  (WM2A1+4608)
#define WPA1T  (WM2A2+4608)
#define WBNS   (WPA1T+1152)
#define WCA1T  (WBNS+192)
#define WCA2T  (WCA1T+9216)
#define WS_Q   870784
#define WS_K   (WS_Q+786432)
#define WS_V   (WS_K+786432)
#define WS_X1  (WS_V+786432+786432)
#define WS_X2  (WS_X1+1572864)
#define WS_X3  (WS_X2+1572864)
#define WS_PA  (WS_X3+1572864)
#define WS_GAP (WS_PA+16384)

__device__ __forceinline__ float gelu_f(float x){
  return 0.5f * x * (1.0f + erff(x * 0.7071067811865476f));
}
__device__ __forceinline__ float sigmoid_f(float x){
  return 1.0f / (1.0f + __expf(-x));
}
__device__ __forceinline__ unsigned short bfr(float f){
  unsigned int u = __float_as_uint(f);
  u += 0x7fffu + ((u >> 16) & 1u);
  return (unsigned short)(u >> 16);
}
__device__ __forceinline__ float bflo16(unsigned short u){ return __uint_as_float(((unsigned int)u) << 16); }
__device__ __forceinline__ float bflo(unsigned int u){ return __uint_as_float(u << 16); }
__device__ __forceinline__ float bfhi(unsigned int u){ return __uint_as_float(u & 0xffff0000u); }
__device__ __forceinline__ void get_ms(const float* st, int b, float& mean, float& inv, float& stdv){
  float s = st[b], s2 = st[4+b];
  mean = s * (1.0f/NELEMF);
  float var = fmaxf(s2 * (1.0f/NELEMF) - mean*mean, 0.0f);
  stdv = sqrtf(var + EPSF);
  inv = 1.0f / stdv;
}
__device__ __forceinline__ float ldf(const float* p, int i){ return p[i]; }
__device__ __forceinline__ float ldf(const unsigned short* p, int i){ return bflo16(p[i]); }
__device__ __forceinline__ void load4(const float* p, float4& v){ v = *(const float4*)p; }
__device__ __forceinline__ void load4(const unsigned short* p, float4& v){
  ushort4 u = *(const ushort4*)p;
  v.x = bflo16(u.x); v.y = bflo16(u.y); v.z = bflo16(u.z); v.w = bflo16(u.w);
}
__device__ __forceinline__ float dotg(const float* qv, const uint4* p){
  uint4 a = p[0], b = p[1];
  float s;
  s  = qv[0]*bflo(a.x);            s = fmaf(qv[1],  bfhi(a.x), s);
  s = fmaf(qv[2],  bflo(a.y), s);  s = fmaf(qv[3],  bfhi(a.y), s);
  s = fmaf(qv[4],  bflo(a.z), s);  s = fmaf(qv[5],  bfhi(a.z), s);
  s = fmaf(qv[6],  bflo(a.w), s);  s = fmaf(qv[7],  bfhi(a.w), s);
  s = fmaf(qv[8],  bflo(b.x), s);  s = fmaf(qv[9],  bfhi(b.x), s);
  s = fmaf(qv[10], bflo(b.y), s);  s = fmaf(qv[11], bfhi(b.y), s);
  s = fmaf(qv[12], bflo(b.z), s);  s = fmaf(qv[13], bfhi(b.z), s);
  s = fmaf(qv[14], bflo(b.w), s);  s = fmaf(qv[15], bfhi(b.w), s);
  return s;
}
__device__ __forceinline__ void pvg(float w, const uint4* p, float* acc){
  uint4 a = p[0], b = p[1];
  acc[0]  = fmaf(w, bflo(a.x), acc[0]);  acc[1]  = fmaf(w, bfhi(a.x), acc[1]);
  acc[2]  = fmaf(w, bflo(a.y), acc[2]);  acc[3]  = fmaf(w, bfhi(a.y), acc[3]);
  acc[4]  = fmaf(w, bflo(a.z), acc[4]);  acc[5]  = fmaf(w, bfhi(a.z), acc[5]);
  acc[6]  = fmaf(w, bflo(a.w), acc[6]);  acc[7]  = fmaf(w, bfhi(a.w), acc[7]);
  acc[8]  = fmaf(w, bflo(b.x), acc[8]);  acc[9]  = fmaf(w, bfhi(b.x), acc[9]);
  acc[10] = fmaf(w, bflo(b.y), acc[10]); acc[11] = fmaf(w, bfhi(b.y), acc[11]);
  acc[12] = fmaf(w, bflo(b.z), acc[12]); acc[13] = fmaf(w, bfhi(b.z), acc[13]);
  acc[14] = fmaf(w, bflo(b.w), acc[14]); acc[15] = fmaf(w, bfhi(b.w), acc[15]);
}

struct KArgs {
  const float *x, *lnw, *lnb, *m1w, *m1b, *m2w, *m2b;
  const float *qkv1w, *qkv1b, *proj1w, *proj1b, *rpb1;
  const float *qkv2w, *qkv2b, *proj2w, *proj2b, *rpb2;
  const float *mw1, *mb1, *mw2, *mb2;
  const float *bng, *bnb, *bnm, *bnv;
  const float *paw1, *pab1, *paw2, *pab2;
  const float *caw1, *cab1, *caw2, *cab2;
  const float *aw1, *ab1, *aw2, *ab2;
  float* ws; float* out;
};

// ---- phase 0: stats(x) + weight prep (grid-stride over 256 blocks x 512 thr) ----
__device__ __forceinline__ void prep_phase(const KArgs& a, float* st, float* lsb){
  int bid = blockIdx.x, tid = threadIdx.x;
  float* ws = a.ws;
  for(int sl = bid; sl < 384; sl += 256){
    int b = sl / CC, c = sl % CC;
    const float4* p4 = (const float4*)(a.x + (size_t)(b*CC + c)*NP);
    float s = 0.f, s2 = 0.f;
    for(int i = tid; i < 1024; i += 512){
      float4 v = p4[i];
      s += v.x + v.y + v.z + v.w;
      s2 = fmaf(v.x, v.x, fmaf(v.y, v.y, fmaf(v.z, v.z, fmaf(v.w, v.w, s2))));
    }
    for(int off = 32; off > 0; off >>= 1){ s += __shfl_down(s, off); s2 += __shfl_down(s2, off); }
    int wid = tid >> 6;
    if((tid & 63) == 0){ lsb[wid] = s; lsb[8+wid] = s2; }
    __syncthreads();
    if(tid == 0){
      float a0 = 0.f, a1 = 0.f;
      #pragma unroll
      for(int i = 0; i < 8; ++i){ a0 += lsb[i]; a1 += lsb[8+i]; }
      atomicAdd(&st[b], a0); atomicAdd(&st[4+b], a1);
    }
    __syncthreads();
  }
  for(int gid = bid*512 + tid; gid < 185952; gid += 256*512){
    if(gid < 27648){ int n = gid/96, c = gid%96; ((unsigned short*)(ws+WQKV1))[gid] = bfr(a.qkv1w[c*288+n]); }
    else if(gid < 55296){ int g = gid-27648; int n = g/96, c = g%96; ((unsigned short*)(ws+WQKV2))[g] = bfr(a.qkv2w[c*288+n]); }
    else if(gid < 64512){ int g = gid-55296; int n = g/96, c = g%96; ((unsigned short*)(ws+WPROJ1))[g] = bfr(a.proj1w[c*96+n]); }
    else if(gid < 73728){ int g = gid-64512; int n = g/96, c = g%96; ((unsigned short*)(ws+WPROJ2))[g] = bfr(a.proj2w[c*96+n]); }
    else if(gid < 110592){ int g = gid-73728; ((unsigned short*)(ws+WMLP1))[g] = bfr(a.mw1[g]); }
    else if(gid < 147456){ int g = gid-110592; ((unsigned short*)(ws+WMLP2))[g] = bfr(a.mw2[g]); }
    else if(gid < 156672){ int g = gid-147456; ((unsigned short*)(ws+WM2A1))[g] = bfr(a.aw1[g]); }
    else if(gid < 165888){ int g = gid-156672; ((unsigned short*)(ws+WM2A2))[g] = bfr(a.aw2[g]); }
    else if(gid < 167040){ int g = gid-165888; int c = g/12, h = g%12; ws[WPA1T + g] = a.paw1[h*96+c]; }
    else if(gid < 167136){ int c = gid-167040;
      float sc = rsqrtf(a.bnv[c] + EPSF) * a.bng[c];
      ws[WBNS + c] = sc;
      ws[WBNS + 96 + c] = a.bnb[c] - a.bnm[c]*sc;
    }
    else if(gid < 167520){ ws[WS_GAP + (gid-167136)] = 0.f; }
    else if(gid < 176736){ int g = gid-167520; int o = g/96, c = g%96; ws[WCA1T + c*96 + o] = a.caw1[g]; }
    else { int g = gid-176736; int o = g/96, c = g%96; ws[WCA2T + c*96 + o] = a.caw2[g]; }
  }
}

// ---- phase: fused LN + QKV GEMM (block = 64-px tile) ----
template<typename AT>
__device__ __forceinline__ void qkv_phase(
    const AT* xin, const float* st,
    const float* lnw, const float* lnb,
    const unsigned short* wT, const float* qb,
    unsigned short* qo, unsigned short* ko, unsigned short* vo,
    char* smbuf, float* scl, float* ofs){
  unsigned short* Atl = (unsigned short*)smbuf;    // [64][104]
  int bid = blockIdx.x, tid = threadIdx.x;
  int m_base = bid*64;
  int b = m_base >> 12, pxl0 = m_base & 4095;
  float mean, inv, stdv; get_ms(st, b, mean, inv, stdv);
  if(tid < 96){ float s = inv*lnw[tid]; scl[tid] = s; ofs[tid] = lnb[tid] - mean*s; }
  __syncthreads();
  const AT* src = xin + (size_t)b*CC*NP + pxl0;
  for(int idx = tid; idx < 96*16; idx += 512){
    int c = idx >> 4, p4 = (idx & 15) << 2;
    float4 v; load4(src + (size_t)c*NP + p4, v);
    float s = scl[c], o = ofs[c];
    Atl[(p4+0)*104 + c] = bfr(fmaf(v.x, s, o));
    Atl[(p4+1)*104 + c] = bfr(fmaf(v.y, s, o));
    Atl[(p4+2)*104 + c] = bfr(fmaf(v.z, s, o));
    Atl[(p4+3)*104 + c] = bfr(fmaf(v.w, s, o));
  }
  __syncthreads();
  int w = tid >> 6, lane = tid & 63, ml = lane & 15, q = lane >> 4;
  int row = w & 3, nh = w >> 2;
  const unsigned short* arow = Atl + (row*16 + ml)*104;
  bf16x8 av[3];
  #pragma unroll
  for(int ks = 0; ks < 3; ++ks) av[ks] = *(const bf16x8*)(arow + ks*32 + q*8);
  f32x4 z = {0.f,0.f,0.f,0.f};
  #pragma unroll
  for(int g0 = 0; g0 < 3; ++g0){
    int g = nh*3 + g0;
    f32x4 acc[3] = {z, z, z};
    #pragma unroll
    for(int ks = 0; ks < 3; ++ks){
      #pragma unroll
      for(int gg = 0; gg < 3; ++gg){
        bf16x8 bv = *(const bf16x8*)(wT + (g*48 + gg*16 + ml)*96 + ks*32 + q*8);
        acc[gg] = MFMA16(av[ks], bv, acc[gg]);
      }
    }
    #pragma unroll
    for(int gg = 0; gg < 3; ++gg){
      int nfb = g*48 + gg*16;
      int t = nfb/96, head = (nfb%96) >> 4;
      float scale = (t == 0) ? 0.25f : 1.0f;
      unsigned short* dst = (t == 0) ? qo : (t == 1) ? ko : vo;
      float bias = qb[nfb + ml];
      #pragma unroll
      for(int r = 0; r < 4; ++r){
        int pxl = pxl0 + row*16 + q*4 + r;
        dst[(((size_t)(b*NHEADS + head))*NP + pxl)*16 + ml] = bfr((acc[gg][r] + bias)*scale);
      }
    }
  }
  __syncthreads();
}

// ---- phase: fused attention + proj + residual + stats (block = (b, x-column)) ----
template<int K, int D, int RPB, typename SCT>
__device__ __forceinline__ void attnproj_phase(
    const unsigned short* qb, const unsigned short* kb,
    const unsigned short* vb, const float* rpb,
    const unsigned short* wT, const float* pb,
    const SCT* scx, const float* st,
    const float* m1w, const float* m1b,
    const float* m2w, const float* m2b,
    unsigned short* dst, float* st_out,
    char* smbuf, float* rpbl, float* lsb){
  unsigned short* attout = (unsigned short*)smbuf;   // [64][104] bf16
  float* T = (float*)smbuf;                          // [96][68] f32 (aliased)
  int b = blockIdx.x >> 6;
  int x = blockIdx.x & 63;
  int tid = threadIdx.x;
  for(int i = tid; i < NHEADS*RPB*RPB; i += 512) rpbl[i] = rpb[i];
  __syncthreads();

  if(tid < 384){
    int head = tid >> 6;
    int y = tid & 63;
    int bh = b*NHEADS + head;
    int gx = (D == 1) ? 0 : (x & (D-1));
    int px = (D == 1) ? x : (x >> 3);
    int Lgx = (64 - gx + D - 1) / D;
    int sx = min(max(px - K/2, 0), Lgx - K);
    int gy = (D == 1) ? 0 : (y & (D-1));
    int py = (D == 1) ? y : (y >> 3);
    int Lgy = (64 - gy + D - 1) / D;
    int sy = min(max(py - K/2, 0), Lgy - K);
    int dxb = sx - px + (K-1);
    int dyb = sy - py + (K-1);
    int pix = x*64 + y;

    float qv[16];
    {
      const uint4* qg = (const uint4*)(qb + ((size_t)bh*NP + pix)*16);
      uint4 qa = qg[0], qb4 = qg[1];
      qv[0]=bflo(qa.x);  qv[1]=bfhi(qa.x);  qv[2]=bflo(qa.y);  qv[3]=bfhi(qa.y);
      qv[4]=bflo(qa.z);  qv[5]=bfhi(qa.z);  qv[6]=bflo(qa.w);  qv[7]=bfhi(qa.w);
      qv[8]=bflo(qb4.x); qv[9]=bfhi(qb4.x); qv[10]=bflo(qb4.y);qv[11]=bfhi(qb4.y);
      qv[12]=bflo(qb4.z);qv[13]=bfhi(qb4.z);qv[14]=bflo(qb4.w);qv[15]=bfhi(qb4.w);
    }
    const unsigned short* kgb = kb + (size_t)bh*NP*16;
    const unsigned short* vgb = vb + (size_t)bh*NP*16;

    float sc[K*K];
    #pragma unroll
    for(int i = 0; i < K; ++i){
      int colx = gx + D*(sx + i);
      const unsigned short* kcol = kgb + (size_t)colx*64*16;
      const float* br = rpbl + (head*RPB + (i + dxb))*RPB + dyb;
      #pragma unroll
      for(int j = 0; j < K; ++j){
        int wwy = gy + D*(sy + j);
        sc[i*K + j] = dotg(qv, (const uint4*)(kcol + wwy*16)) + br[j];
      }
    }
    float mx = -1e30f;
    #pragma unroll
    for(int n = 0; n < K*K; ++n) mx = fmaxf(mx, sc[n]);
    float sum = 0.f;
    #pragma unroll
    for(int n = 0; n < K*K; ++n){ float e = __expf(sc[n] - mx); sc[n] = e; sum += e; }
    float rs = 1.0f / sum;
    float acc[16];
    #pragma unroll
    for(int d = 0; d < 16; ++d) acc[d] = 0.f;
    #pragma unroll
    for(int i = 0; i < K; ++i){
      int colx = gx + D*(sx + i);
      const unsigned short* vcol = vgb + (size_t)colx*64*16;
      #pragma unroll
      for(int j = 0; j < K; ++j){
        int wwy = gy + D*(sy + j);
        pvg(sc[i*K + j] * rs, (const uint4*)(vcol + wwy*16), acc);
      }
    }
    unsigned int ow[8];
    #pragma unroll
    for(int p = 0; p < 8; ++p)
      ow[p] = (unsigned int)bfr(acc[2*p]) | ((unsigned int)bfr(acc[2*p+1]) << 16);
    unsigned short* op = attout + y*104 + head*16;
    *(uint4*)op = make_uint4(ow[0], ow[1], ow[2], ow[3]);
    *(uint4*)(op + 8) = make_uint4(ow[4], ow[5], ow[6], ow[7]);
  }
  __syncthreads();

  // proj GEMM 64x96 (K=96): 8 waves = 4 rowgroups x 2 N-halves(48)
  int w = tid >> 6, lane = tid & 63, ml = lane & 15, q = lane >> 4;
  int row = w & 3, nh = w >> 2;
  f32x4 z = {0.f,0.f,0.f,0.f};
  f32x4 acc[3] = {z, z, z};
  {
    const unsigned short* arow = attout + (row*16 + ml)*104;
    #pragma unroll
    for(int ks = 0; ks < 3; ++ks){
      bf16x8 av = *(const bf16x8*)(arow + ks*32 + q*8);
      #pragma unroll
      for(int g0 = 0; g0 < 3; ++g0){
        int g = nh*3 + g0;
        bf16x8 bv = *(const bf16x8*)(wT + (g*16 + ml)*96 + ks*32 + q*8);
        acc[g0] = MFMA16(av, bv, acc[g0]);
      }
    }
  }
  __syncthreads();
  #pragma unroll
  for(int g0 = 0; g0 < 3; ++g0){
    int g = nh*3 + g0;
    #pragma unroll
    for(int r = 0; r < 4; ++r)
      T[(g*16 + ml)*68 + row*16 + q*4 + r] = acc[g0][r];
  }
  __syncthreads();
  int pxl0 = x*64;
  float mean, inv, stdv; get_ms(st, b, mean, inv, stdv);
  float s = 0.f, s2 = 0.f;
  for(int idx = tid; idx < 96*64; idx += 512){
    int n = idx >> 6, p = idx & 63;
    float rsf = fmaf(m1w[n], stdv, m1b[n]);
    float rbf = fmaf(m2w[n], mean, m2b[n]);
    int ad = (b*CC + n)*NP + pxl0 + p;
    float val = ldf(scx, ad) + (T[n*68 + p] + pb[n])*rsf + rbf;
    dst[ad] = bfr(val);
    s += val; s2 = fmaf(val, val, s2);
  }
  for(int off = 32; off > 0; off >>= 1){ s += __shfl_down(s, off); s2 += __shfl_down(s2, off); }
  if(lane == 0){ lsb[w] = s; lsb[8+w] = s2; }
  __syncthreads();
  if(tid == 0){
    float a0 = 0.f, a1 = 0.f;
    #pragma unroll
    for(int i = 0; i < 8; ++i){ a0 += lsb[i]; a1 += lsb[8+i]; }
    atomicAdd(&st_out[b], a0);
    atomicAdd(&st_out[4+b], a1);
  }
  __syncthreads();
}

// ---- phase: fused MLP + x3 + pa + gap ----
__device__ __forceinline__ void mlp_phase(
    const unsigned short* xin, const float* st,
    const float* lnw, const float* lnb,
    const unsigned short* w1T, const float* b1,
    const unsigned short* w2T, const float* b2,
    const unsigned short* scx,
    const float* m1w, const float* m1b,
    const float* m2w, const float* m2b,
    float* dst,
    const float* bns, const float* pw1t,
    const float* pb1, const float* pw2,
    const float* pb2, float* pa, float* gap,
    char* smbuf, float* scl, float* ofs){
  unsigned short* Atl  = (unsigned short*)smbuf;
  unsigned short* hidL = (unsigned short*)(smbuf + 13312);   // [64][392] bf16
  float* T = (float*)(smbuf + 13312);                        // [96][68] (aliased)
  float* gpart = (float*)smbuf;                              // [8][96] (aliased, pa phase)
  int bid = blockIdx.x, tid = threadIdx.x;
  int m_base = bid*64;
  int b = m_base >> 12, pxl0 = m_base & 4095;
  float mean, inv, stdv; get_ms(st, b, mean, inv, stdv);
  if(tid < 96){ float s = inv*lnw[tid]; scl[tid] = s; ofs[tid] = lnb[tid] - mean*s; }
  __syncthreads();
  const unsigned short* src = xin + (size_t)b*CC*NP + pxl0;
  for(int idx = tid; idx < 96*16; idx += 512){
    int c = idx >> 4, p4 = (idx & 15) << 2;
    float4 v; load4(src + (size_t)c*NP + p4, v);
    float s = scl[c], o = ofs[c];
    Atl[(p4+0)*104 + c] = bfr(fmaf(v.x, s, o));
    Atl[(p4+1)*104 + c] = bfr(fmaf(v.y, s, o));
    Atl[(p4+2)*104 + c] = bfr(fmaf(v.z, s, o));
    Atl[(p4+3)*104 + c] = bfr(fmaf(v.w, s, o));
  }
  __syncthreads();
  int w = tid >> 6, lane = tid & 63, ml = lane & 15, q = lane >> 4;
  int row = w & 3, nh = w >> 2;
  f32x4 z = {0.f,0.f,0.f,0.f};
  {
    const unsigned short* arow = Atl + (row*16 + ml)*104;
    bf16x8 av[3];
    #pragma unroll
    for(int ks = 0; ks < 3; ++ks) av[ks] = *(const bf16x8*)(arow + ks*32 + q*8);
    #pragma unroll
    for(int g0 = 0; g0 < 4; ++g0){
      int g = nh*4 + g0;
      f32x4 acc[3] = {z, z, z};
      #pragma unroll
      for(int ks = 0; ks < 3; ++ks){
        #pragma unroll
        for(int gg = 0; gg < 3; ++gg){
          bf16x8 bv = *(const bf16x8*)(w1T + (g*48 + gg*16 + ml)*96 + ks*32 + q*8);
          acc[gg] = MFMA16(av[ks], bv, acc[gg]);
        }
      }
      #pragma unroll
      for(int gg = 0; gg < 3; ++gg){
        int n = g*48 + gg*16 + ml;
        float bias = b1[n];
        #pragma unroll
        for(int r = 0; r < 4; ++r)
          hidL[(row*16 + q*4 + r)*392 + n] = bfr(fmaxf(acc[gg][r] + bias, 0.f));
      }
    }
  }
  __syncthreads();
  f32x4 acc2[3] = {z, z, z};
  {
    const unsigned short* arow = hidL + (row*16 + ml)*392;
    #pragma unroll
    for(int ks = 0; ks < 12; ++ks){
      bf16x8 av = *(const bf16x8*)(arow + ks*32 + q*8);
      #pragma unroll
      for(int g0 = 0; g0 < 3; ++g0){
        int g = nh*3 + g0;
        bf16x8 bv = *(const bf16x8*)(w2T + (g*16 + ml)*384 + ks*32 + q*8);
        acc2[g0] = MFMA16(av, bv, acc2[g0]);
      }
    }
  }
  __syncthreads();
  #pragma unroll
  for(int g0 = 0; g0 < 3; ++g0){
    int g = nh*3 + g0;
    #pragma unroll
    for(int r = 0; r < 4; ++r)
      T[(g*16 + ml)*68 + row*16 + q*4 + r] = acc2[g0][r];
  }
  __syncthreads();
  for(int idx = tid; idx < 96*64; idx += 512){
    int n = idx >> 6, px = idx & 63;
    float rsf = fmaf(m1w[n], stdv, m1b[n]);
    float rbf = fmaf(m2w[n], mean, m2b[n]);
    int ad = (b*CC + n)*NP + pxl0 + px;
    float val = ldf(scx, ad) + (T[n*68 + px] + b2[n])*rsf + rbf;
    dst[ad] = val;
    T[n*68 + px] = val;
  }
  __syncthreads();
  int pxq = tid >> 3, t = tid & 7;
  float yvv[12], acc[12];
  #pragma unroll
  for(int h = 0; h < 12; ++h) acc[h] = 0.f;
  #pragma unroll 6
  for(int cc = 0; cc < 12; ++cc){
    int c = t*12 + cc;
    float yv = fmaf(T[c*68 + pxq], bns[c], bns[96 + c]);
    yvv[cc] = yv;
    #pragma unroll
    for(int h = 0; h < 12; ++h) acc[h] = fmaf(yv, pw1t[c*12 + h], acc[h]);
  }
  #pragma unroll
  for(int h = 0; h < 12; ++h){
    acc[h] += __shfl_xor(acc[h], 1);
    acc[h] += __shfl_xor(acc[h], 2);
    acc[h] += __shfl_xor(acc[h], 4);
  }
  float s = pb2[0];
  #pragma unroll
  for(int h = 0; h < 12; ++h) s = fmaf(gelu_f(acc[h] + pb1[h]), pw2[h], s);
  float pav = sigmoid_f(s);
  if(t == 0) pa[b*NP + pxl0 + pxq] = pav;
  #pragma unroll 6
  for(int cc = 0; cc < 12; ++cc){
    float g = yvv[cc] * pav;
    g += __shfl_xor(g, 8);  g += __shfl_xor(g, 16); g += __shfl_xor(g, 32);
    if(lane < 8) gpart[w*96 + lane*12 + cc] = g;
  }
  __syncthreads();
  if(tid < 96){
    int c = tid;
    float v = 0.f;
    #pragma unroll
    for(int ww = 0; ww < 8; ++ww) v += gpart[ww*96 + c];
    atomicAdd(&gap[b*96 + c], v * (1.0f/4096.0f));
  }
  __syncthreads();
}

// ---- phase: fused ca + m2a ----
__device__ __forceinline__ void m2a_phase(
    const float* x3, const float* bns,
    const float* pa, const float* gap,
    const float* cw1T, const float* cb1,
    const float* cw2T, const float* cb2,
    const unsigned short* w1T, const float* b1,
    const unsigned short* w2T, const float* b2,
    const float* scx, float* outp,
    char* smbuf, float* scl, float* ofs,
    float* pal, float* gl, float* tl){
  unsigned short* Atl = (unsigned short*)smbuf;
  unsigned short* tl2 = (unsigned short*)(smbuf + 13312);
  float* T = (float*)smbuf;
  int bid = blockIdx.x, tid = threadIdx.x;
  int m_base = bid*64;
  int b = m_base >> 12, pxl0 = m_base & 4095;
  if(tid < 96) gl[tid] = gap[b*96 + tid];
  if(tid >= 128 && tid < 192) pal[tid-128] = pa[m_base + (tid-128)];
  __syncthreads();
  if(tid < 96){
    float a = cb1[tid];
    #pragma unroll 8
    for(int c = 0; c < 96; ++c) a = fmaf(gl[c], cw1T[c*96 + tid], a);
    tl[tid] = gelu_f(a);
  }
  __syncthreads();
  if(tid < 96){
    float a = cb2[tid];
    #pragma unroll 8
    for(int c = 0; c < 96; ++c) a = fmaf(tl[c], cw2T[c*96 + tid], a);
    float cv = sigmoid_f(a);
    scl[tid] = bns[tid]*cv; ofs[tid] = bns[96+tid]*cv;
  }
  __syncthreads();
  const float* src = x3 + (size_t)b*CC*NP + pxl0;
  for(int idx = tid; idx < 96*16; idx += 512){
    int c = idx >> 4, p4 = (idx & 15) << 2;
    float4 v = *(const float4*)(src + (size_t)c*NP + p4);
    float s = scl[c], o = ofs[c];
    Atl[(p4+0)*104 + c] = bfr(fmaf(v.x, s, o) * pal[p4+0]);
    Atl[(p4+1)*104 + c] = bfr(fmaf(v.y, s, o) * pal[p4+1]);
    Atl[(p4+2)*104 + c] = bfr(fmaf(v.z, s, o) * pal[p4+2]);
    Atl[(p4+3)*104 + c] = bfr(fmaf(v.w, s, o) * pal[p4+3]);
  }
  __syncthreads();
  int w = tid >> 6, lane = tid & 63, ml = lane & 15, q = lane >> 4;
  int row = w & 3, nh = w >> 2;
  f32x4 z = {0.f,0.f,0.f,0.f};
  f32x4 acc1[3] = {z, z, z};
  {
    const unsigned short* arow = Atl + (row*16 + ml)*104;
    #pragma unroll
    for(int ks = 0; ks < 3; ++ks){
      bf16x8 av = *(const bf16x8*)(arow + ks*32 + q*8);
      #pragma unroll
      for(int g0 = 0; g0 < 3; ++g0){
        int g = nh*3 + g0;
        bf16x8 bv = *(const bf16x8*)(w1T + (g*16 + ml)*96 + ks*32 + q*8);
        acc1[g0] = MFMA16(av, bv, acc1[g0]);
      }
    }
  }
  #pragma unroll
  for(int g0 = 0; g0 < 3; ++g0){
    int g = nh*3 + g0;
    float bias = b1[g*16 + ml];
    #pragma unroll
    for(int r = 0; r < 4; ++r)
      tl2[(row*16 + q*4 + r)*104 + g*16 + ml] = bfr(gelu_f(acc1[g0][r] + bias));
  }
  __syncthreads();
  f32x4 acc2[3] = {z, z, z};
  {
    const unsigned short* arow = tl2 + (row*16 + ml)*104;
    #pragma unroll
    for(int ks = 0; ks < 3; ++ks){
      bf16x8 av = *(const bf16x8*)(arow + ks*32 + q*8);
      #pragma unroll
      for(int g0 = 0; g0 < 3; ++g0){
        int g = nh*3 + g0;
        bf16x8 bv = *(const bf16x8*)(w2T + (g*16 + ml)*96 + ks*32 + q*8);
        acc2[g0] = MFMA16(av, bv, acc2[g0]);
      }
    }
  }
  __syncthreads();
  #pragma unroll
  for(int g0 = 0; g0 < 3; ++g0){
    int g = nh*3 + g0;
    #pragma unroll
    for(int r = 0; r < 4; ++r)
      T[(g*16 + ml)*68 + row*16 + q*4 + r] = acc2[g0][r];
  }
  __syncthreads();
  for(int idx = tid; idx < 96*64; idx += 512){
    int n = idx >> 6, p = idx & 63;
    int ad = (b*CC + n)*NP + pxl0 + p;
    outp[ad] = scx[ad] + T[n*68 + p] + b2[n];
  }
}

// ---- the mega-kernel: 256 blocks x 512 threads, cooperative ----
__global__ void __launch_bounds__(512, 1) mega_kernel(KArgs a){
  cg::grid_group grid = cg::this_grid();
  __shared__ __align__(16) char smraw[63488];
  __shared__ float scl[96], ofs[96], lsb[32];
  __shared__ float pal[64], gl[96], tl[96];
  __shared__ float rpbl[NHEADS*13*13];

  float* ws  = a.ws;
  float* st0 = ws;
  float* st1 = ws + 8;
  float* st2 = ws + 16;
  unsigned short* q   = (unsigned short*)(ws + WS_Q);
  unsigned short* k   = (unsigned short*)(ws + WS_K);
  unsigned short* v   = (unsigned short*)(ws + WS_V);
  unsigned short* x1b = (unsigned short*)(ws + WS_X1);
  unsigned short* x2b = (unsigned short*)(ws + WS_X2);
  float* x3  = ws + WS_X3;
  float* pab = ws + WS_PA;
  float* gpb = ws + WS_GAP;
  float* bns = ws + WBNS;

  prep_phase(a, st0, lsb);
  grid.sync();

  qkv_phase<float>(a.x, st0, a.lnw, a.lnb,
      (unsigned short*)(ws+WQKV1), a.qkv1b, q, k, v, smraw, scl, ofs);
  grid.sync();

  attnproj_phase<7,1,13,float>(q, k, v, a.rpb1,
      (unsigned short*)(ws+WPROJ1), a.proj1b, a.x, st0,
      a.m1w, a.m1b, a.m2w, a.m2b, x1b, st1, smraw, rpbl, lsb);
  grid.sync();

  qkv_phase<unsigned short>(x1b, st1, a.lnw, a.lnb,
      (unsigned short*)(ws+WQKV2), a.qkv2b, q, k, v, smraw, scl, ofs);
  grid.sync();

  attnproj_phase<5,8,9,unsigned short>(q, k, v, a.rpb2,
      (unsigned short*)(ws+WPROJ2), a.proj2b, x1b, st1,
      a.m1w, a.m1b, a.m2w, a.m2b, x2b, st2, smraw, rpbl, lsb);
  grid.sync();

  mlp_phase(x2b, st2, a.lnw, a.lnb,
      (unsigned short*)(ws+WMLP1), a.mb1, (unsigned short*)(ws+WMLP2), a.mb2,
      x1b, a.m1w, a.m1b, a.m2w, a.m2b, x3,
      bns, ws + WPA1T, a.pab1, a.paw2, a.pab2, pab, gpb, smraw, scl, ofs);
  grid.sync();

  m2a_phase(x3, bns, pab, gpb,
      ws + WCA1T, a.cab1, ws + WCA2T, a.cab2,
      (unsigned short*)(ws+WM2A1), a.ab1, (unsigned short*)(ws+WM2A2), a.ab2,
      x3, a.out, smraw, scl, ofs, pal, gl, tl);
}

extern "C" void kernel_launch(void* const* d_in, const int* in_sizes, int n_in,
                              void* d_out, int out_size, void* d_ws, size_t ws_size,
                              hipStream_t stream){
  (void)in_sizes; (void)n_in; (void)out_size; (void)ws_size;
  KArgs ka;
  ka.x      = (const float*)d_in[0];
  ka.lnw    = (const float*)d_in[1];
  ka.lnb    = (const float*)d_in[2];
  ka.m1w    = (const float*)d_in[3];
  ka.m1b    = (const float*)d_in[4];
  ka.m2w    = (const float*)d_in[5];
  ka.m2b    = (const float*)d_in[6];
  ka.qkv1w  = (const float*)d_in[7];
  ka.qkv1b  = (const float*)d_in[8];
  ka.proj1w = (const float*)d_in[9];
  ka.proj1b = (const float*)d_in[10];
  ka.rpb1   = (const float*)d_in[11];
  ka.qkv2w  = (const float*)d_in[12];
  ka.qkv2b  = (const float*)d_in[13];
  ka.proj2w = (const float*)d_in[14];
  ka.proj2b = (const float*)d_in[15];
  ka.rpb2   = (const float*)d_in[16];
  ka.mw1    = (const float*)d_in[17];
  ka.mb1    = (const float*)d_in[18];
  ka.mw2    = (const float*)d_in[19];
  ka.mb2    = (const float*)d_in[20];
  ka.bng    = (const float*)d_in[21];
  ka.bnb    = (const float*)d_in[22];
  ka.bnm    = (const float*)d_in[23];
  ka.bnv    = (const float*)d_in[24];
  ka.paw1   = (const float*)d_in[25];
  ka.pab1   = (const float*)d_in[26];
  ka.paw2   = (const float*)d_in[27];
  ka.pab2   = (const float*)d_in[28];
  ka.caw1   = (const float*)d_in[29];
  ka.cab1   = (const float*)d_in[30];
  ka.caw2   = (const float*)d_in[31];
  ka.cab2   = (const float*)d_in[32];
  ka.aw1    = (const float*)d_in[33];
  ka.ab1    = (const float*)d_in[34];
  ka.aw2    = (const float*)d_in[35];
  ka.ab2    = (const float*)d_in[36];
  ka.ws     = (float*)d_ws;
  ka.out    = (float*)d_out;

  hipMemsetAsync(d_ws, 0, 64*sizeof(float), stream);
  void* kargs[] = { &ka };
  hipLaunchCooperativeKernel((void*)mega_kernel, dim3(256), dim3(512),
                             kargs, 0, stream);
}

// Round 10
// 326.640 us; speedup vs baseline: 1.4446x; 1.4446x over previous
//
#include <hip/hip_runtime.h>
#include <math.h>

#define CC 96
#define NP 4096
#define NHEADS 6
#define NELEMF 393216.0f
#define EPSF 1e-5f

typedef __attribute__((ext_vector_type(8))) short bf16x8;
typedef __attribute__((ext_vector_type(4))) float f32x4;
#define MFMA16(a,b,c) __builtin_amdgcn_mfma_f32_16x16x32_bf16(a,b,c,0,0,0)

// ---- workspace layout (float offsets) ----
#define WQKV1  64
#define WQKV2  (WQKV1+13824)
#define WPROJ1 (WQKV2+13824)
#define WPROJ2 (WPROJ1+4608)
#define WMLP1  (WPROJ2+4608)
#define WMLP2  (WMLP1+18432)
#define WM2A1  (WMLP2+18432)
#define WM2A2  (WM2A1+4608)
#define WPA1T  (WM2A2+4608)
#define WBNS   (WPA1T+1152)
#define WCA1T  (WBNS+192)
#define WCA2T  (WCA1T+9216)
#define WS_Q   870784
#define WS_K   (WS_Q+786432)
#define WS_V   (WS_K+786432)
#define WS_X1  (WS_V+786432+786432)
#define WS_X2  (WS_X1+1572864)
#define WS_X3  (WS_X2+1572864)
#define WS_PA  (WS_X3+1572864)
#define WS_GAP (WS_PA+16384)

__device__ __forceinline__ float gelu_f(float x){
  return 0.5f * x * (1.0f + erff(x * 0.7071067811865476f));
}
__device__ __forceinline__ float sigmoid_f(float x){
  return 1.0f / (1.0f + __expf(-x));
}
__device__ __forceinline__ unsigned short bfr(float f){
  unsigned int u = __float_as_uint(f);
  u += 0x7fffu + ((u >> 16) & 1u);
  return (unsigned short)(u >> 16);
}
__device__ __forceinline__ float bflo16(unsigned short u){ return __uint_as_float(((unsigned int)u) << 16); }
__device__ __forceinline__ float bflo(unsigned int u){ return __uint_as_float(u << 16); }
__device__ __forceinline__ float bfhi(unsigned int u){ return __uint_as_float(u & 0xffff0000u); }
__device__ __forceinline__ void get_ms(const float* st, int b, float& mean, float& inv, float& stdv){
  float s = st[b], s2 = st[4+b];
  mean = s * (1.0f/NELEMF);
  float var = fmaxf(s2 * (1.0f/NELEMF) - mean*mean, 0.0f);
  stdv = sqrtf(var + EPSF);
  inv = 1.0f / stdv;
}
__device__ __forceinline__ float ldf(const float* p, int i){ return p[i]; }
__device__ __forceinline__ float ldf(const unsigned short* p, int i){ return bflo16(p[i]); }
__device__ __forceinline__ void load4(const float* p, float4& v){ v = *(const float4*)p; }
__device__ __forceinline__ void load4(const unsigned short* p, float4& v){
  ushort4 u = *(const ushort4*)p;
  v.x = bflo16(u.x); v.y = bflo16(u.y); v.z = bflo16(u.z); v.w = bflo16(u.w);
}
__device__ __forceinline__ float dotg(const float* qv, const uint4* p){
  uint4 a = p[0], b = p[1];
  float s;
  s  = qv[0]*bflo(a.x);            s = fmaf(qv[1],  bfhi(a.x), s);
  s = fmaf(qv[2],  bflo(a.y), s);  s = fmaf(qv[3],  bfhi(a.y), s);
  s = fmaf(qv[4],  bflo(a.z), s);  s = fmaf(qv[5],  bfhi(a.z), s);
  s = fmaf(qv[6],  bflo(a.w), s);  s = fmaf(qv[7],  bfhi(a.w), s);
  s = fmaf(qv[8],  bflo(b.x), s);  s = fmaf(qv[9],  bfhi(b.x), s);
  s = fmaf(qv[10], bflo(b.y), s);  s = fmaf(qv[11], bfhi(b.y), s);
  s = fmaf(qv[12], bflo(b.z), s);  s = fmaf(qv[13], bfhi(b.z), s);
  s = fmaf(qv[14], bflo(b.w), s);  s = fmaf(qv[15], bfhi(b.w), s);
  return s;
}
__device__ __forceinline__ void pvg(float w, const uint4* p, float* acc){
  uint4 a = p[0], b = p[1];
  acc[0]  = fmaf(w, bflo(a.x), acc[0]);  acc[1]  = fmaf(w, bfhi(a.x), acc[1]);
  acc[2]  = fmaf(w, bflo(a.y), acc[2]);  acc[3]  = fmaf(w, bfhi(a.y), acc[3]);
  acc[4]  = fmaf(w, bflo(a.z), acc[4]);  acc[5]  = fmaf(w, bfhi(a.z), acc[5]);
  acc[6]  = fmaf(w, bflo(a.w), acc[6]);  acc[7]  = fmaf(w, bfhi(a.w), acc[7]);
  acc[8]  = fmaf(w, bflo(b.x), acc[8]);  acc[9]  = fmaf(w, bfhi(b.x), acc[9]);
  acc[10] = fmaf(w, bflo(b.y), acc[10]); acc[11] = fmaf(w, bfhi(b.y), acc[11]);
  acc[12] = fmaf(w, bflo(b.z), acc[12]); acc[13] = fmaf(w, bfhi(b.z), acc[13]);
  acc[14] = fmaf(w, bflo(b.w), acc[14]); acc[15] = fmaf(w, bfhi(b.w), acc[15]);
}
// XCD-aware bijective swizzle for 256-block grids (8 XCDs x 32 consecutive tiles)
__device__ __forceinline__ int xswz(int bid){ return ((bid & 7) << 5) | (bid >> 3); }

// ---- static-bound attention halves (keeps sc[] in VGPRs — no scratch) ----
template<int NI, int K, int D>
__device__ __forceinline__ float attn_scores(
    int i0, const float* qv, const unsigned short* kgb,
    int gx, int sx, int gy, int sy,
    const float* br0, int rpb_stride, float* sc){
  float mx = -1e30f;
  #pragma unroll
  for(int ii = 0; ii < NI; ++ii){
    int i = i0 + ii;
    int colx = gx + D*(sx + i);
    const unsigned short* kcol = kgb + (size_t)colx*64*16;
    const float* br = br0 + i*rpb_stride;
    #pragma unroll
    for(int j = 0; j < K; ++j){
      int wwy = gy + D*(sy + j);
      float s = dotg(qv, (const uint4*)(kcol + wwy*16)) + br[j];
      sc[ii*K + j] = s;
      mx = fmaxf(mx, s);
    }
  }
  return mx;
}
template<int NI, int K>
__device__ __forceinline__ float attn_expsum(float* sc, float mx){
  float sum = 0.f;
  #pragma unroll
  for(int n = 0; n < NI*K; ++n){ float e = __expf(sc[n] - mx); sc[n] = e; sum += e; }
  return sum;
}
template<int NI, int K, int D>
__device__ __forceinline__ void attn_pv(
    int i0, const float* sc, float rs, const unsigned short* vgb,
    int gx, int sx, int gy, int sy, float* acc){
  #pragma unroll
  for(int ii = 0; ii < NI; ++ii){
    int i = i0 + ii;
    int colx = gx + D*(sx + i);
    const unsigned short* vcol = vgb + (size_t)colx*64*16;
    #pragma unroll
    for(int j = 0; j < K; ++j){
      int wwy = gy + D*(sy + j);
      pvg(sc[ii*K + j] * rs, (const uint4*)(vcol + wwy*16), acc);
    }
  }
}

// ---- combined: stats(x) for blocks <384, weight prep + gap zero for blocks >=384 ----
__global__ void prep_stats_kernel(const float* __restrict__ x, float* __restrict__ st,
                             const float* __restrict__ q1, const float* __restrict__ q2,
                             const float* __restrict__ p1, const float* __restrict__ p2,
                             const float* __restrict__ w1, const float* __restrict__ w2,
                             const float* __restrict__ a1, const float* __restrict__ a2,
                             const float* __restrict__ pw1,
                             const float* __restrict__ bg, const float* __restrict__ bb,
                             const float* __restrict__ bm, const float* __restrict__ bv,
                             const float* __restrict__ cw1, const float* __restrict__ cw2,
                             float* __restrict__ ws){
  if(blockIdx.x < 384){
    int b = blockIdx.x / CC, c = blockIdx.x % CC;
    const float4* p4 = (const float4*)(x + (size_t)(b*CC + c)*NP);
    float s = 0.f, s2 = 0.f;
    for(int i = threadIdx.x; i < 1024; i += 256){
      float4 v = p4[i];
      s += v.x + v.y + v.z + v.w;
      s2 = fmaf(v.x, v.x, fmaf(v.y, v.y, fmaf(v.z, v.z, fmaf(v.w, v.w, s2))));
    }
    for(int off = 32; off > 0; off >>= 1){ s += __shfl_down(s, off); s2 += __shfl_down(s2, off); }
    __shared__ float ls[8];
    int wid = threadIdx.x >> 6;
    if((threadIdx.x & 63) == 0){ ls[wid] = s; ls[4+wid] = s2; }
    __syncthreads();
    if(threadIdx.x == 0){
      atomicAdd(&st[b],   ls[0]+ls[1]+ls[2]+ls[3]);
      atomicAdd(&st[4+b], ls[4]+ls[5]+ls[6]+ls[7]);
    }
    return;
  }
  int gid = (blockIdx.x - 384)*256 + threadIdx.x;
  if(gid < 27648){ int n = gid/96, c = gid%96; ((unsigned short*)(ws+WQKV1))[gid] = bfr(q1[c*288+n]); }
  else if(gid < 55296){ int g = gid-27648; int n = g/96, c = g%96; ((unsigned short*)(ws+WQKV2))[g] = bfr(q2[c*288+n]); }
  else if(gid < 64512){ int g = gid-55296; int n = g/96, c = g%96; ((unsigned short*)(ws+WPROJ1))[g] = bfr(p1[c*96+n]); }
  else if(gid < 73728){ int g = gid-64512; int n = g/96, c = g%96; ((unsigned short*)(ws+WPROJ2))[g] = bfr(p2[c*96+n]); }
  else if(gid < 110592){ int g = gid-73728; ((unsigned short*)(ws+WMLP1))[g] = bfr(w1[g]); }
  else if(gid < 147456){ int g = gid-110592; ((unsigned short*)(ws+WMLP2))[g] = bfr(w2[g]); }
  else if(gid < 156672){ int g = gid-147456; ((unsigned short*)(ws+WM2A1))[g] = bfr(a1[g]); }
  else if(gid < 165888){ int g = gid-156672; ((unsigned short*)(ws+WM2A2))[g] = bfr(a2[g]); }
  else if(gid < 167040){ int g = gid-165888; int c = g/12, h = g%12; ws[WPA1T + g] = pw1[h*96+c]; }
  else if(gid < 167136){ int c = gid-167040;
    float sc = rsqrtf(bv[c] + EPSF) * bg[c];
    ws[WBNS + c] = sc;
    ws[WBNS + 96 + c] = bb[c] - bm[c]*sc;
  }
  else if(gid < 167520){ ws[WS_GAP + (gid-167136)] = 0.f; }
  else if(gid < 176736){ int g = gid-167520; int o = g/96, c = g%96; ws[WCA1T + c*96 + o] = cw1[g]; }
  else if(gid < 185952){ int g = gid-176736; int o = g/96, c = g%96; ws[WCA2T + c*96 + o] = cw2[g]; }
}

// ---- fused LN + QKV GEMM: M=64-px tile, 1024 thr (16 waves = 4 rows x 4 N-stripes) ----
template<typename AT>
__global__ void __launch_bounds__(1024) gemm_qkv_kernel(
    const AT* __restrict__ xin, const float* __restrict__ st,
    const float* __restrict__ lnw, const float* __restrict__ lnb,
    const unsigned short* __restrict__ wT, const float* __restrict__ qb,
    unsigned short* __restrict__ qo, unsigned short* __restrict__ ko, unsigned short* __restrict__ vo){
  __shared__ unsigned short Atl[64*104];
  __shared__ float scl[96], ofs[96];
  int wid = xswz(blockIdx.x);
  int m_base = wid*64;
  int b = m_base >> 12, pxl0 = m_base & 4095;
  float mean, inv, stdv; get_ms(st, b, mean, inv, stdv);
  int tid = threadIdx.x;
  if(tid < 96){ float s = inv*lnw[tid]; scl[tid] = s; ofs[tid] = lnb[tid] - mean*s; }
  __syncthreads();
  const AT* src = xin + (size_t)b*CC*NP + pxl0;
  for(int idx = tid; idx < 96*16; idx += 1024){
    int c = idx >> 4, p4 = (idx & 15) << 2;
    float4 v; load4(src + (size_t)c*NP + p4, v);
    float s = scl[c], o = ofs[c];
    Atl[(p4+0)*104 + c] = bfr(fmaf(v.x, s, o));
    Atl[(p4+1)*104 + c] = bfr(fmaf(v.y, s, o));
    Atl[(p4+2)*104 + c] = bfr(fmaf(v.z, s, o));
    Atl[(p4+3)*104 + c] = bfr(fmaf(v.w, s, o));
  }
  __syncthreads();
  int w = tid >> 6, lane = tid & 63, ml = lane & 15, q = lane >> 4;
  int row = w & 3, nh = w >> 2;   // nh in 0..3
  const unsigned short* arow = Atl + (row*16 + ml)*104;
  bf16x8 av[3];
  #pragma unroll
  for(int ks = 0; ks < 3; ++ks) av[ks] = *(const bf16x8*)(arow + ks*32 + q*8);
  f32x4 z = {0.f,0.f,0.f,0.f};
  for(int g = nh; g < 18; g += 4){       // 18 N-groups of 16, striped over 4 wave-columns
    f32x4 acc = z;
    #pragma unroll
    for(int ks = 0; ks < 3; ++ks){
      bf16x8 bv = *(const bf16x8*)(wT + (g*16 + ml)*96 + ks*32 + q*8);
      acc = MFMA16(av[ks], bv, acc);
    }
    int nfb = g*16;
    int t = nfb/96, head = (nfb%96) >> 4;
    float scale = (t == 0) ? 0.25f : 1.0f;
    unsigned short* dst = (t == 0) ? qo : (t == 1) ? ko : vo;
    float bias = qb[nfb + ml];
    #pragma unroll
    for(int r = 0; r < 4; ++r){
      int pxl = pxl0 + row*16 + q*4 + r;
      dst[(((size_t)(b*NHEADS + head))*NP + pxl)*16 + ml] = bfr((acc[r] + bias)*scale);
    }
  }
}

// ---- FUSED attention + proj + residual + stats: block = (b, x-column), 1024 thr ----
// Phase A: 768 thr = 2 per (head, y), static row-split + shfl_xor(1) combine
// Phase B: 16-wave MFMA proj 64x96x96 from LDS + epilogue
template<int K, int D, int RPB, typename SCT>
__global__ void __launch_bounds__(1024) attnproj_kernel(
    const unsigned short* __restrict__ qb, const unsigned short* __restrict__ kb,
    const unsigned short* __restrict__ vb, const float* __restrict__ rpb,
    const unsigned short* __restrict__ wT, const float* __restrict__ pb,
    const SCT* __restrict__ scx, const float* __restrict__ st,
    const float* __restrict__ m1w, const float* __restrict__ m1b,
    const float* __restrict__ m2w, const float* __restrict__ m2b,
    unsigned short* __restrict__ dst, float* __restrict__ st_out){
  __shared__ __align__(16) char smbuf[26624];    // attout [64][104] bf16 | T [96][68] f32 (aliased)
  __shared__ float rpbl[NHEADS*RPB*RPB];
  __shared__ float ls[32];
  unsigned short* attout = (unsigned short*)smbuf;
  float* T = (float*)smbuf;
  int wid = xswz(blockIdx.x);
  int b = wid >> 6;
  int x = wid & 63;
  int tid = threadIdx.x;
  for(int i = tid; i < NHEADS*RPB*RPB; i += 1024) rpbl[i] = rpb[i];
  __syncthreads();

  constexpr int KLO = (K+1)/2;
  constexpr int KH2 = K - KLO;
  if(tid < 768){
    int half = tid & 1;
    int hy = tid >> 1;
    int head = hy >> 6;
    int y = hy & 63;
    int bh = b*NHEADS + head;
    int gx = (D == 1) ? 0 : (x & (D-1));
    int px = (D == 1) ? x : (x >> 3);
    int Lgx = (64 - gx + D - 1) / D;
    int sx = min(max(px - K/2, 0), Lgx - K);
    int gy = (D == 1) ? 0 : (y & (D-1));
    int py = (D == 1) ? y : (y >> 3);
    int Lgy = (64 - gy + D - 1) / D;
    int sy = min(max(py - K/2, 0), Lgy - K);
    int dxb = sx - px + (K-1);
    int dyb = sy - py + (K-1);
    int pix = x*64 + y;

    float qv[16];
    {
      const uint4* qg = (const uint4*)(qb + ((size_t)bh*NP + pix)*16);
      uint4 qa = qg[0], qb4 = qg[1];
      qv[0]=bflo(qa.x);  qv[1]=bfhi(qa.x);  qv[2]=bflo(qa.y);  qv[3]=bfhi(qa.y);
      qv[4]=bflo(qa.z);  qv[5]=bfhi(qa.z);  qv[6]=bflo(qa.w);  qv[7]=bfhi(qa.w);
      qv[8]=bflo(qb4.x); qv[9]=bfhi(qb4.x); qv[10]=bflo(qb4.y);qv[11]=bfhi(qb4.y);
      qv[12]=bflo(qb4.z);qv[13]=bfhi(qb4.z);qv[14]=bflo(qb4.w);qv[15]=bfhi(qb4.w);
    }
    const unsigned short* kgb = kb + (size_t)bh*NP*16;
    const unsigned short* vgb = vb + (size_t)bh*NP*16;
    const float* br0 = rpbl + (head*RPB + dxb)*RPB + dyb;

    float sc[KLO*K];
    float mx;
    if(half == 0) mx = attn_scores<KLO,K,D>(0,   qv, kgb, gx, sx, gy, sy, br0, RPB, sc);
    else          mx = attn_scores<KH2,K,D>(KLO, qv, kgb, gx, sx, gy, sy, br0, RPB, sc);
    mx = fmaxf(mx, __shfl_xor(mx, 1));
    float sum;
    if(half == 0) sum = attn_expsum<KLO,K>(sc, mx);
    else          sum = attn_expsum<KH2,K>(sc, mx);
    sum += __shfl_xor(sum, 1);
    float rs = 1.0f / sum;
    float acc[16];
    #pragma unroll
    for(int d = 0; d < 16; ++d) acc[d] = 0.f;
    if(half == 0) attn_pv<KLO,K,D>(0,   sc, rs, vgb, gx, sx, gy, sy, acc);
    else          attn_pv<KH2,K,D>(KLO, sc, rs, vgb, gx, sx, gy, sy, acc);
    #pragma unroll
    for(int d = 0; d < 16; ++d) acc[d] += __shfl_xor(acc[d], 1);
    if(half == 0){
      unsigned int ow[8];
      #pragma unroll
      for(int p = 0; p < 8; ++p)
        ow[p] = (unsigned int)bfr(acc[2*p]) | ((unsigned int)bfr(acc[2*p+1]) << 16);
      unsigned short* op = attout + y*104 + head*16;
      *(uint4*)op = make_uint4(ow[0], ow[1], ow[2], ow[3]);
      *(uint4*)(op + 8) = make_uint4(ow[4], ow[5], ow[6], ow[7]);
    }
  }
  __syncthreads();

  // ---- proj GEMM 64x96 (K=96): 16 waves = 4 rowgroups x 4 N-stripes over 6 groups ----
  int w = tid >> 6, lane = tid & 63, ml = lane & 15, q = lane >> 4;
  int row = w & 3, nh = w >> 2;    // nh 0..3
  int gA = nh, gB = nh + 4;
  bool hasB = (gB < 6);
  f32x4 z = {0.f,0.f,0.f,0.f};
  f32x4 accA = z, accB = z;
  {
    const unsigned short* arow = attout + (row*16 + ml)*104;
    bf16x8 av[3];
    #pragma unroll
    for(int ks = 0; ks < 3; ++ks) av[ks] = *(const bf16x8*)(arow + ks*32 + q*8);
    #pragma unroll
    for(int ks = 0; ks < 3; ++ks){
      bf16x8 bvA = *(const bf16x8*)(wT + (gA*16 + ml)*96 + ks*32 + q*8);
      accA = MFMA16(av[ks], bvA, accA);
    }
    if(hasB){
      #pragma unroll
      for(int ks = 0; ks < 3; ++ks){
        bf16x8 bvB = *(const bf16x8*)(wT + (gB*16 + ml)*96 + ks*32 + q*8);
        accB = MFMA16(av[ks], bvB, accB);
      }
    }
  }
  __syncthreads();      // attout reads done; region becomes T
  #pragma unroll
  for(int r = 0; r < 4; ++r)
    T[(gA*16 + ml)*68 + row*16 + q*4 + r] = accA[r];
  if(hasB){
    #pragma unroll
    for(int r = 0; r < 4; ++r)
      T[(gB*16 + ml)*68 + row*16 + q*4 + r] = accB[r];
  }
  __syncthreads();
  // ---- epilogue: residual + rescale/rebias + bf16 store + fp32 stats ----
  int pxl0 = x*64;
  float mean, inv, stdv; get_ms(st, b, mean, inv, stdv);
  float s = 0.f, s2 = 0.f;
  for(int idx = tid; idx < 96*64; idx += 1024){
    int n = idx >> 6, p = idx & 63;
    float rsf = fmaf(m1w[n], stdv, m1b[n]);
    float rbf = fmaf(m2w[n], mean, m2b[n]);
    int ad = (b*CC + n)*NP + pxl0 + p;
    float val = ldf(scx, ad) + (T[n*68 + p] + pb[n])*rsf + rbf;
    dst[ad] = bfr(val);
    s += val; s2 = fmaf(val, val, s2);
  }
  for(int off = 32; off > 0; off >>= 1){ s += __shfl_down(s, off); s2 += __shfl_down(s2, off); }
  if(lane == 0){ ls[w] = s; ls[16+w] = s2; }
  __syncthreads();
  if(tid == 0){
    float a0 = 0.f, a1 = 0.f;
    #pragma unroll
    for(int i = 0; i < 16; ++i){ a0 += ls[i]; a1 += ls[16+i]; }
    atomicAdd(&st_out[b], a0);
    atomicAdd(&st_out[4+b], a1);
  }
}

// ---- FUSED MLP: LN(x2) -> GEMM1(N=384,relu) -> GEMM2(K=384) -> +x1 -> x3 -> pa + gap (1024 thr) ----
__global__ void __launch_bounds__(1024) gemm_mlp_kernel(
    const unsigned short* __restrict__ xin, const float* __restrict__ st,
    const float* __restrict__ lnw, const float* __restrict__ lnb,
    const unsigned short* __restrict__ w1T, const float* __restrict__ b1,
    const unsigned short* __restrict__ w2T, const float* __restrict__ b2,
    const unsigned short* __restrict__ scx,
    const float* __restrict__ m1w, const float* __restrict__ m1b,
    const float* __restrict__ m2w, const float* __restrict__ m2b,
    float* __restrict__ dst,
    const float* __restrict__ bns, const float* __restrict__ pw1t,
    const float* __restrict__ pb1, const float* __restrict__ pw2,
    const float* __restrict__ pb2, float* __restrict__ pa,
    float* __restrict__ gap){
  __shared__ __align__(16) char smbuf[63488];     // Atl 13312 | hidL 50176
  __shared__ float scl[96], ofs[96];
  unsigned short* Atl  = (unsigned short*)smbuf;
  unsigned short* hidL = (unsigned short*)(smbuf + 13312);   // [64][392] bf16
  float* T = (float*)(smbuf + 13312);                        // [96][68] (aliased)
  float* gpart = (float*)smbuf;                              // [8][96] (aliased, pa phase)
  int wid = xswz(blockIdx.x);
  int m_base = wid*64;
  int b = m_base >> 12, pxl0 = m_base & 4095;
  float mean, inv, stdv; get_ms(st, b, mean, inv, stdv);
  int tid = threadIdx.x;
  if(tid < 96){ float s = inv*lnw[tid]; scl[tid] = s; ofs[tid] = lnb[tid] - mean*s; }
  __syncthreads();
  const unsigned short* src = xin + (size_t)b*CC*NP + pxl0;
  for(int idx = tid; idx < 96*16; idx += 1024){
    int c = idx >> 4, p4 = (idx & 15) << 2;
    float4 v; load4(src + (size_t)c*NP + p4, v);
    float s = scl[c], o = ofs[c];
    Atl[(p4+0)*104 + c] = bfr(fmaf(v.x, s, o));
    Atl[(p4+1)*104 + c] = bfr(fmaf(v.y, s, o));
    Atl[(p4+2)*104 + c] = bfr(fmaf(v.z, s, o));
    Atl[(p4+3)*104 + c] = bfr(fmaf(v.w, s, o));
  }
  __syncthreads();
  int w = tid >> 6, lane = tid & 63, ml = lane & 15, q = lane >> 4;
  int row = w & 3, nh = w >> 2;   // nh 0..3
  f32x4 z = {0.f,0.f,0.f,0.f};
  // GEMM1: 64x384, hidden -> LDS (relu); 8 g-groups: g = nh*2 + g0
  {
    const unsigned short* arow = Atl + (row*16 + ml)*104;
    bf16x8 av[3];
    #pragma unroll
    for(int ks = 0; ks < 3; ++ks) av[ks] = *(const bf16x8*)(arow + ks*32 + q*8);
    #pragma unroll
    for(int g0 = 0; g0 < 2; ++g0){
      int g = nh*2 + g0;
      f32x4 acc[3] = {z, z, z};
      #pragma unroll
      for(int ks = 0; ks < 3; ++ks){
        #pragma unroll
        for(int gg = 0; gg < 3; ++gg){
          bf16x8 bv = *(const bf16x8*)(w1T + (g*48 + gg*16 + ml)*96 + ks*32 + q*8);
          acc[gg] = MFMA16(av[ks], bv, acc[gg]);
        }
      }
      #pragma unroll
      for(int gg = 0; gg < 3; ++gg){
        int n = g*48 + gg*16 + ml;
        float bias = b1[n];
        #pragma unroll
        for(int r = 0; r < 4; ++r)
          hidL[(row*16 + q*4 + r)*392 + n] = bfr(fmaxf(acc[gg][r] + bias, 0.f));
      }
    }
  }
  __syncthreads();
  // GEMM2: 64x96, K=384 from LDS hidden; 6 N-groups striped over 4 nh
  int gA = nh, gB = nh + 4;
  bool hasB = (gB < 6);
  f32x4 accA = z, accB = z;
  {
    const unsigned short* arow = hidL + (row*16 + ml)*392;
    for(int ks = 0; ks < 12; ++ks){
      bf16x8 av = *(const bf16x8*)(arow + ks*32 + q*8);
      bf16x8 bvA = *(const bf16x8*)(w2T + (gA*16 + ml)*384 + ks*32 + q*8);
      accA = MFMA16(av, bvA, accA);
      if(hasB){
        bf16x8 bvB = *(const bf16x8*)(w2T + (gB*16 + ml)*384 + ks*32 + q*8);
        accB = MFMA16(av, bvB, accB);
      }
    }
  }
  __syncthreads();      // hidL reads done; region becomes T
  #pragma unroll
  for(int r = 0; r < 4; ++r)
    T[(gA*16 + ml)*68 + row*16 + q*4 + r] = accA[r];
  if(hasB){
    #pragma unroll
    for(int r = 0; r < 4; ++r)
      T[(gB*16 + ml)*68 + row*16 + q*4 + r] = accB[r];
  }
  __syncthreads();
  // epilogue: x3 = sc + (T + b2)*rsf + rbf; store global and back into T for pa phase
  for(int idx = tid; idx < 96*64; idx += 1024){
    int n = idx >> 6, px = idx & 63;
    float rsf = fmaf(m1w[n], stdv, m1b[n]);
    float rbf = fmaf(m2w[n], mean, m2b[n]);
    int ad = (b*CC + n)*NP + pxl0 + px;
    float val = ldf(scx, ad) + (T[n*68 + px] + b2[n])*rsf + rbf;
    dst[ad] = val;
    T[n*68 + px] = val;
  }
  __syncthreads();
  // ---- fused pixel-attention + gap partials (first 512 threads; no inner barriers) ----
  if(tid < 512){
    int pxq = tid >> 3, t = tid & 7;
    float yvv[12], acc[12];
    #pragma unroll
    for(int h = 0; h < 12; ++h) acc[h] = 0.f;
    #pragma unroll 6
    for(int cc = 0; cc < 12; ++cc){
      int c = t*12 + cc;
      float yv = fmaf(T[c*68 + pxq], bns[c], bns[96 + c]);
      yvv[cc] = yv;
      #pragma unroll
      for(int h = 0; h < 12; ++h) acc[h] = fmaf(yv, pw1t[c*12 + h], acc[h]);
    }
    #pragma unroll
    for(int h = 0; h < 12; ++h){
      acc[h] += __shfl_xor(acc[h], 1);
      acc[h] += __shfl_xor(acc[h], 2);
      acc[h] += __shfl_xor(acc[h], 4);
    }
    float s = pb2[0];
    #pragma unroll
    for(int h = 0; h < 12; ++h) s = fmaf(gelu_f(acc[h] + pb1[h]), pw2[h], s);
    float pav = sigmoid_f(s);
    if(t == 0) pa[b*NP + pxl0 + pxq] = pav;
    #pragma unroll 6
    for(int cc = 0; cc < 12; ++cc){
      float g = yvv[cc] * pav;
      g += __shfl_xor(g, 8);  g += __shfl_xor(g, 16); g += __shfl_xor(g, 32);
      if(lane < 8) gpart[w*96 + lane*12 + cc] = g;
    }
  }
  __syncthreads();
  if(tid < 96){
    int c = tid;
    float v = 0.f;
    #pragma unroll
    for(int ww = 0; ww < 8; ++ww) v += gpart[ww*96 + c];
    atomicAdd(&gap[b*96 + c], v * (1.0f/4096.0f));
  }
}

// ---- fused m2a + ca: ca from gap, BN*pa*ca -> GEMM1 -> gelu -> GEMM2 -> +x3 (1024 thr) ----
__global__ void __launch_bounds__(1024) gemm_m2a_kernel(
    const float* __restrict__ x3, const float* __restrict__ bns,
    const float* __restrict__ pa, const float* __restrict__ gap,
    const float* __restrict__ cw1T, const float* __restrict__ cb1,
    const float* __restrict__ cw2T, const float* __restrict__ cb2,
    const unsigned short* __restrict__ w1T, const float* __restrict__ b1,
    const unsigned short* __restrict__ w2T, const float* __restrict__ b2,
    const float* __restrict__ scx, float* __restrict__ outp){
  __shared__ __align__(16) char smbuf[26624];
  __shared__ float scl[96], ofs[96], pal[64];
  __shared__ float gl[96], tl[96];
  unsigned short* Atl = (unsigned short*)smbuf;
  unsigned short* tl2 = (unsigned short*)(smbuf + 13312);
  float* T = (float*)smbuf;
  int wid = xswz(blockIdx.x);
  int m_base = wid*64;
  int b = m_base >> 12, pxl0 = m_base & 4095;
  int tid = threadIdx.x;
  if(tid < 96) gl[tid] = gap[b*96 + tid];
  if(tid >= 128 && tid < 192) pal[tid-128] = pa[m_base + (tid-128)];
  __syncthreads();
  if(tid < 96){
    float a = cb1[tid];
    #pragma unroll 8
    for(int c = 0; c < 96; ++c) a = fmaf(gl[c], cw1T[c*96 + tid], a);
    tl[tid] = gelu_f(a);
  }
  __syncthreads();
  if(tid < 96){
    float a = cb2[tid];
    #pragma unroll 8
    for(int c = 0; c < 96; ++c) a = fmaf(tl[c], cw2T[c*96 + tid], a);
    float cv = sigmoid_f(a);
    scl[tid] = bns[tid]*cv; ofs[tid] = bns[96+tid]*cv;
  }
  __syncthreads();
  const float* src = x3 + (size_t)b*CC*NP + pxl0;
  for(int idx = tid; idx < 96*16; idx += 1024){
    int c = idx >> 4, p4 = (idx & 15) << 2;
    float4 v = *(const float4*)(src + (size_t)c*NP + p4);
    float s = scl[c], o = ofs[c];
    Atl[(p4+0)*104 + c] = bfr(fmaf(v.x, s, o) * pal[p4+0]);
    Atl[(p4+1)*104 + c] = bfr(fmaf(v.y, s, o) * pal[p4+1]);
    Atl[(p4+2)*104 + c] = bfr(fmaf(v.z, s, o) * pal[p4+2]);
    Atl[(p4+3)*104 + c] = bfr(fmaf(v.w, s, o) * pal[p4+3]);
  }
  __syncthreads();
  int w = tid >> 6, lane = tid & 63, ml = lane & 15, q = lane >> 4;
  int row = w & 3, nh = w >> 2;   // nh 0..3
  f32x4 z = {0.f,0.f,0.f,0.f};
  // GEMM1: 6 N-groups striped; write tl2 per-group (separate LDS region)
  {
    const unsigned short* arow = Atl + (row*16 + ml)*104;
    bf16x8 av[3];
    #pragma unroll
    for(int ks = 0; ks < 3; ++ks) av[ks] = *(const bf16x8*)(arow + ks*32 + q*8);
    for(int g = nh; g < 6; g += 4){
      f32x4 acc1 = z;
      #pragma unroll
      for(int ks = 0; ks < 3; ++ks){
        bf16x8 bv = *(const bf16x8*)(w1T + (g*16 + ml)*96 + ks*32 + q*8);
        acc1 = MFMA16(av[ks], bv, acc1);
      }
      float bias = b1[g*16 + ml];
      #pragma unroll
      for(int r = 0; r < 4; ++r)
        tl2[(row*16 + q*4 + r)*104 + g*16 + ml] = bfr(gelu_f(acc1[r] + bias));
    }
  }
  __syncthreads();
  // GEMM2: 6 N-groups striped; hold accs across barrier (T spans Atl+tl2)
  int gA = nh, gB = nh + 4;
  bool hasB = (gB < 6);
  f32x4 accA = z, accB = z;
  {
    const unsigned short* arow = tl2 + (row*16 + ml)*104;
    #pragma unroll
    for(int ks = 0; ks < 3; ++ks){
      bf16x8 av = *(const bf16x8*)(arow + ks*32 + q*8);
      bf16x8 bvA = *(const bf16x8*)(w2T + (gA*16 + ml)*96 + ks*32 + q*8);
      accA = MFMA16(av, bvA, accA);
      if(hasB){
        bf16x8 bvB = *(const bf16x8*)(w2T + (gB*16 + ml)*96 + ks*32 + q*8);
        accB = MFMA16(av, bvB, accB);
      }
    }
  }
  __syncthreads();
  #pragma unroll
  for(int r = 0; r < 4; ++r)
    T[(gA*16 + ml)*68 + row*16 + q*4 + r] = accA[r];
  if(hasB){
    #pragma unroll
    for(int r = 0; r < 4; ++r)
      T[(gB*16 + ml)*68 + row*16 + q*4 + r] = accB[r];
  }
  __syncthreads();
  for(int idx = tid; idx < 96*64; idx += 1024){
    int n = idx >> 6, p = idx & 63;
    int ad = (b*CC + n)*NP + pxl0 + p;
    outp[ad] = scx[ad] + T[n*68 + p] + b2[n];
  }
}

extern "C" void kernel_launch(void* const* d_in, const int* in_sizes, int n_in,
                              void* d_out, int out_size, void* d_ws, size_t ws_size,
                              hipStream_t stream){
  (void)in_sizes; (void)n_in; (void)out_size; (void)ws_size;
  const float* x     = (const float*)d_in[0];
  const float* lnw   = (const float*)d_in[1];
  const float* lnb   = (const float*)d_in[2];
  const float* m1w   = (const float*)d_in[3];
  const float* m1b   = (const float*)d_in[4];
  const float* m2w   = (const float*)d_in[5];
  const float* m2b   = (const float*)d_in[6];
  const float* qkv1w = (const float*)d_in[7];
  const float* qkv1b = (const float*)d_in[8];
  const float* proj1w= (const float*)d_in[9];
  const float* proj1b= (const float*)d_in[10];
  const float* rpb1  = (const float*)d_in[11];
  const float* qkv2w = (const float*)d_in[12];
  const float* qkv2b = (const float*)d_in[13];
  const float* proj2w= (const float*)d_in[14];
  const float* proj2b= (const float*)d_in[15];
  const float* rpb2  = (const float*)d_in[16];
  const float* mw1   = (const float*)d_in[17];
  const float* mb1   = (const float*)d_in[18];
  const float* mw2   = (const float*)d_in[19];
  const float* mb2   = (const float*)d_in[20];
  const float* bng   = (const float*)d_in[21];
  const float* bnb   = (const float*)d_in[22];
  const float* bnm   = (const float*)d_in[23];
  const float* bnv   = (const float*)d_in[24];
  const float* paw1  = (const float*)d_in[25];
  const float* pab1  = (const float*)d_in[26];
  const float* paw2  = (const float*)d_in[27];
  const float* pab2  = (const float*)d_in[28];
  const float* caw1  = (const float*)d_in[29];
  const float* cab1  = (const float*)d_in[30];
  const float* caw2  = (const float*)d_in[31];
  const float* cab2  = (const float*)d_in[32];
  const float* aw1   = (const float*)d_in[33];
  const float* ab1   = (const float*)d_in[34];
  const float* aw2   = (const float*)d_in[35];
  const float* ab2   = (const float*)d_in[36];

  float* ws  = (float*)d_ws;
  float* out = (float*)d_out;
  float* st0 = ws;
  float* st1 = ws + 8;
  float* st2 = ws + 16;
  unsigned short* q     = (unsigned short*)(ws + WS_Q);
  unsigned short* k     = (unsigned short*)(ws + WS_K);
  unsigned short* v     = (unsigned short*)(ws + WS_V);
  unsigned short* x1b   = (unsigned short*)(ws + WS_X1);
  unsigned short* x2b   = (unsigned short*)(ws + WS_X2);
  float* x3  = ws + WS_X3;
  float* pab = ws + WS_PA;
  float* gpb = ws + WS_GAP;
  float* bns = ws + WBNS;

  hipMemsetAsync(d_ws, 0, 64*sizeof(float), stream);
  prep_stats_kernel<<<1111, 256, 0, stream>>>(x, st0, qkv1w, qkv2w, proj1w, proj2w,
                                              mw1, mw2, aw1, aw2, paw1,
                                              bng, bnb, bnm, bnv, caw1, caw2, ws);

  // stage 1: attn k=7 d=1 (fused attn+proj)
  gemm_qkv_kernel<float><<<256, 1024, 0, stream>>>(x, st0, lnw, lnb,
      (unsigned short*)(ws+WQKV1), qkv1b, q, k, v);
  attnproj_kernel<7,1,13,float><<<256, 1024, 0, stream>>>(q, k, v, rpb1,
      (unsigned short*)(ws+WPROJ1), proj1b, x, st0, m1w, m1b, m2w, m2b, x1b, st1);

  // stage 2: attn k=5 d=8 (fused attn+proj)
  gemm_qkv_kernel<unsigned short><<<256, 1024, 0, stream>>>(x1b, st1, lnw, lnb,
      (unsigned short*)(ws+WQKV2), qkv2b, q, k, v);
  attnproj_kernel<5,8,9,unsigned short><<<256, 1024, 0, stream>>>(q, k, v, rpb2,
      (unsigned short*)(ws+WPROJ2), proj2b, x1b, st1, m1w, m1b, m2w, m2b, x2b, st2);

  // stage 3: fused MLP (sc = x1) + pa + gap
  gemm_mlp_kernel<<<256, 1024, 0, stream>>>(x2b, st2, lnw, lnb,
      (unsigned short*)(ws+WMLP1), mb1, (unsigned short*)(ws+WMLP2), mb2,
      x1b, m1w, m1b, m2w, m2b, x3,
      bns, ws + WPA1T, pab1, paw2, pab2, pab, gpb);

  // stage 4: fused (ca + m2a)
  gemm_m2a_kernel<<<256, 1024, 0, stream>>>(x3, bns, pab, gpb,
                                            ws + WCA1T, cab1, ws + WCA2T, cab2,
                                            (unsigned short*)(ws+WM2A1), ab1,
                                            (unsigned short*)(ws+WM2A2), ab2, x3, out);
}

// Round 11
// 326.039 us; speedup vs baseline: 1.4473x; 1.0018x over previous
//
#include <hip/hip_runtime.h>
#include <math.h>

#define CC 96
#define NP 4096
#define NHEADS 6
#define NELEMF 393216.0f
#define EPSF 1e-5f

typedef __attribute__((ext_vector_type(8))) short bf16x8;
typedef __attribute__((ext_vector_type(4))) float f32x4;
#define MFMA16(a,b,c) __builtin_amdgcn_mfma_f32_16x16x32_bf16(a,b,c,0,0,0)

// ---- workspace layout (float offsets) ----
#define WQKV1  64
#define WQKV2  (WQKV1+13824)
#define WPROJ1 (WQKV2+13824)
#define WPROJ2 (WPROJ1+4608)
#define WMLP1  (WPROJ2+4608)
#define WMLP2  (WMLP1+18432)
#define WM2A1  (WMLP2+18432)
#define WM2A2  (WM2A1+4608)
#define WPA1T  (WM2A2+4608)
#define WBNS   (WPA1T+1152)
#define WCA1T  (WBNS+192)
#define WCA2T  (WCA1T+9216)
#define WS_Q   870784
#define WS_K   (WS_Q+786432)
#define WS_V   (WS_K+786432)
#define WS_X1  (WS_V+786432+786432)
#define WS_X2  (WS_X1+1572864)
#define WS_X3  (WS_X2+1572864)
#define WS_PA  (WS_X3+1572864)
#define WS_GAP (WS_PA+16384)

__device__ __forceinline__ float gelu_f(float x){
  return 0.5f * x * (1.0f + erff(x * 0.7071067811865476f));
}
__device__ __forceinline__ float sigmoid_f(float x){
  return 1.0f / (1.0f + __expf(-x));
}
__device__ __forceinline__ unsigned short bfr(float f){
  unsigned int u = __float_as_uint(f);
  u += 0x7fffu + ((u >> 16) & 1u);
  return (unsigned short)(u >> 16);
}
__device__ __forceinline__ float bflo16(unsigned short u){ return __uint_as_float(((unsigned int)u) << 16); }
__device__ __forceinline__ float bflo(unsigned int u){ return __uint_as_float(u << 16); }
__device__ __forceinline__ float bfhi(unsigned int u){ return __uint_as_float(u & 0xffff0000u); }
__device__ __forceinline__ void get_ms(const float* st, int b, float& mean, float& inv, float& stdv){
  float s = st[b], s2 = st[4+b];
  mean = s * (1.0f/NELEMF);
  float var = fmaxf(s2 * (1.0f/NELEMF) - mean*mean, 0.0f);
  stdv = sqrtf(var + EPSF);
  inv = 1.0f / stdv;
}
__device__ __forceinline__ float ldf(const float* p, int i){ return p[i]; }
__device__ __forceinline__ float ldf(const unsigned short* p, int i){ return bflo16(p[i]); }
__device__ __forceinline__ void load4(const float* p, float4& v){ v = *(const float4*)p; }
__device__ __forceinline__ void load4(const unsigned short* p, float4& v){
  ushort4 u = *(const ushort4*)p;
  v.x = bflo16(u.x); v.y = bflo16(u.y); v.z = bflo16(u.z); v.w = bflo16(u.w);
}
__device__ __forceinline__ float dotg(const float* qv, const uint4* p){
  uint4 a = p[0], b = p[1];
  float s;
  s  = qv[0]*bflo(a.x);            s = fmaf(qv[1],  bfhi(a.x), s);
  s = fmaf(qv[2],  bflo(a.y), s);  s = fmaf(qv[3],  bfhi(a.y), s);
  s = fmaf(qv[4],  bflo(a.z), s);  s = fmaf(qv[5],  bfhi(a.z), s);
  s = fmaf(qv[6],  bflo(a.w), s);  s = fmaf(qv[7],  bfhi(a.w), s);
  s = fmaf(qv[8],  bflo(b.x), s);  s = fmaf(qv[9],  bfhi(b.x), s);
  s = fmaf(qv[10], bflo(b.y), s);  s = fmaf(qv[11], bfhi(b.y), s);
  s = fmaf(qv[12], bflo(b.z), s);  s = fmaf(qv[13], bfhi(b.z), s);
  s = fmaf(qv[14], bflo(b.w), s);  s = fmaf(qv[15], bfhi(b.w), s);
  return s;
}
__device__ __forceinline__ void pvg(float w, const uint4* p, float* acc){
  uint4 a = p[0], b = p[1];
  acc[0]  = fmaf(w, bflo(a.x), acc[0]);  acc[1]  = fmaf(w, bfhi(a.x), acc[1]);
  acc[2]  = fmaf(w, bflo(a.y), acc[2]);  acc[3]  = fmaf(w, bfhi(a.y), acc[3]);
  acc[4]  = fmaf(w, bflo(a.z), acc[4]);  acc[5]  = fmaf(w, bfhi(a.z), acc[5]);
  acc[6]  = fmaf(w, bflo(a.w), acc[6]);  acc[7]  = fmaf(w, bfhi(a.w), acc[7]);
  acc[8]  = fmaf(w, bflo(b.x), acc[8]);  acc[9]  = fmaf(w, bfhi(b.x), acc[9]);
  acc[10] = fmaf(w, bflo(b.y), acc[10]); acc[11] = fmaf(w, bfhi(b.y), acc[11]);
  acc[12] = fmaf(w, bflo(b.z), acc[12]); acc[13] = fmaf(w, bfhi(b.z), acc[13]);
  acc[14] = fmaf(w, bflo(b.w), acc[14]); acc[15] = fmaf(w, bfhi(b.w), acc[15]);
}
// XCD-aware bijective swizzle for 256-block grids (8 XCDs x 32 consecutive tiles)
__device__ __forceinline__ int xswz(int bid){ return ((bid & 7) << 5) | (bid >> 3); }

// ---- static-bound attention halves (keeps sc[] in VGPRs — no scratch) ----
template<int NI, int K, int D>
__device__ __forceinline__ float attn_scores(
    int i0, const float* qv, const unsigned short* kgb,
    int gx, int sx, int gy, int sy,
    const float* br0, int rpb_stride, float* sc){
  float mx = -1e30f;
  #pragma unroll
  for(int ii = 0; ii < NI; ++ii){
    int i = i0 + ii;
    int colx = gx + D*(sx + i);
    const unsigned short* kcol = kgb + (size_t)colx*64*16;
    const float* br = br0 + i*rpb_stride;
    #pragma unroll
    for(int j = 0; j < K; ++j){
      int wwy = gy + D*(sy + j);
      float s = dotg(qv, (const uint4*)(kcol + wwy*16)) + br[j];
      sc[ii*K + j] = s;
      mx = fmaxf(mx, s);
    }
  }
  return mx;
}
template<int NI, int K>
__device__ __forceinline__ float attn_expsum(float* sc, float mx){
  float sum = 0.f;
  #pragma unroll
  for(int n = 0; n < NI*K; ++n){ float e = __expf(sc[n] - mx); sc[n] = e; sum += e; }
  return sum;
}
template<int NI, int K, int D>
__device__ __forceinline__ void attn_pv(
    int i0, const float* sc, float rs, const unsigned short* vgb,
    int gx, int sx, int gy, int sy, float* acc){
  #pragma unroll
  for(int ii = 0; ii < NI; ++ii){
    int i = i0 + ii;
    int colx = gx + D*(sx + i);
    const unsigned short* vcol = vgb + (size_t)colx*64*16;
    #pragma unroll
    for(int j = 0; j < K; ++j){
      int wwy = gy + D*(sy + j);
      pvg(sc[ii*K + j] * rs, (const uint4*)(vcol + wwy*16), acc);
    }
  }
}

// ---- combined: stats(x) for blocks <384, weight prep + gap zero for blocks >=384 ----
__global__ void prep_stats_kernel(const float* __restrict__ x, float* __restrict__ st,
                             const float* __restrict__ q1, const float* __restrict__ q2,
                             const float* __restrict__ p1, const float* __restrict__ p2,
                             const float* __restrict__ w1, const float* __restrict__ w2,
                             const float* __restrict__ a1, const float* __restrict__ a2,
                             const float* __restrict__ pw1,
                             const float* __restrict__ bg, const float* __restrict__ bb,
                             const float* __restrict__ bm, const float* __restrict__ bv,
                             const float* __restrict__ cw1, const float* __restrict__ cw2,
                             float* __restrict__ ws){
  if(blockIdx.x < 384){
    int b = blockIdx.x / CC, c = blockIdx.x % CC;
    const float4* p4 = (const float4*)(x + (size_t)(b*CC + c)*NP);
    float s = 0.f, s2 = 0.f;
    for(int i = threadIdx.x; i < 1024; i += 256){
      float4 v = p4[i];
      s += v.x + v.y + v.z + v.w;
      s2 = fmaf(v.x, v.x, fmaf(v.y, v.y, fmaf(v.z, v.z, fmaf(v.w, v.w, s2))));
    }
    for(int off = 32; off > 0; off >>= 1){ s += __shfl_down(s, off); s2 += __shfl_down(s2, off); }
    __shared__ float ls[8];
    int wid = threadIdx.x >> 6;
    if((threadIdx.x & 63) == 0){ ls[wid] = s; ls[4+wid] = s2; }
    __syncthreads();
    if(threadIdx.x == 0){
      atomicAdd(&st[b],   ls[0]+ls[1]+ls[2]+ls[3]);
      atomicAdd(&st[4+b], ls[4]+ls[5]+ls[6]+ls[7]);
    }
    return;
  }
  int gid = (blockIdx.x - 384)*256 + threadIdx.x;
  if(gid < 27648){ int n = gid/96, c = gid%96; ((unsigned short*)(ws+WQKV1))[gid] = bfr(q1[c*288+n]); }
  else if(gid < 55296){ int g = gid-27648; int n = g/96, c = g%96; ((unsigned short*)(ws+WQKV2))[g] = bfr(q2[c*288+n]); }
  else if(gid < 64512){ int g = gid-55296; int n = g/96, c = g%96; ((unsigned short*)(ws+WPROJ1))[g] = bfr(p1[c*96+n]); }
  else if(gid < 73728){ int g = gid-64512; int n = g/96, c = g%96; ((unsigned short*)(ws+WPROJ2))[g] = bfr(p2[c*96+n]); }
  else if(gid < 110592){ int g = gid-73728; ((unsigned short*)(ws+WMLP1))[g] = bfr(w1[g]); }
  else if(gid < 147456){ int g = gid-110592; ((unsigned short*)(ws+WMLP2))[g] = bfr(w2[g]); }
  else if(gid < 156672){ int g = gid-147456; ((unsigned short*)(ws+WM2A1))[g] = bfr(a1[g]); }
  else if(gid < 165888){ int g = gid-156672; ((unsigned short*)(ws+WM2A2))[g] = bfr(a2[g]); }
  else if(gid < 167040){ int g = gid-165888; int c = g/12, h = g%12; ws[WPA1T + g] = pw1[h*96+c]; }
  else if(gid < 167136){ int c = gid-167040;
    float sc = rsqrtf(bv[c] + EPSF) * bg[c];
    ws[WBNS + c] = sc;
    ws[WBNS + 96 + c] = bb[c] - bm[c]*sc;
  }
  else if(gid < 167520){ ws[WS_GAP + (gid-167136)] = 0.f; }
  else if(gid < 176736){ int g = gid-167520; int o = g/96, c = g%96; ws[WCA1T + c*96 + o] = cw1[g]; }
  else if(gid < 185952){ int g = gid-176736; int o = g/96, c = g%96; ws[WCA2T + c*96 + o] = cw2[g]; }
}

// ---- fused LN + QKV GEMM: M=64-px tile, 1024 thr (16 waves = 4 rows x 4 N-stripes) ----
template<typename AT>
__global__ void __launch_bounds__(1024, 4) gemm_qkv_kernel(
    const AT* __restrict__ xin, const float* __restrict__ st,
    const float* __restrict__ lnw, const float* __restrict__ lnb,
    const unsigned short* __restrict__ wT, const float* __restrict__ qb,
    unsigned short* __restrict__ qo, unsigned short* __restrict__ ko, unsigned short* __restrict__ vo){
  __shared__ unsigned short Atl[64*104];
  __shared__ float scl[96], ofs[96];
  int wid = xswz(blockIdx.x);
  int m_base = wid*64;
  int b = m_base >> 12, pxl0 = m_base & 4095;
  float mean, inv, stdv; get_ms(st, b, mean, inv, stdv);
  int tid = threadIdx.x;
  if(tid < 96){ float s = inv*lnw[tid]; scl[tid] = s; ofs[tid] = lnb[tid] - mean*s; }
  __syncthreads();
  const AT* src = xin + (size_t)b*CC*NP + pxl0;
  for(int idx = tid; idx < 96*16; idx += 1024){
    int c = idx >> 4, p4 = (idx & 15) << 2;
    float4 v; load4(src + (size_t)c*NP + p4, v);
    float s = scl[c], o = ofs[c];
    Atl[(p4+0)*104 + c] = bfr(fmaf(v.x, s, o));
    Atl[(p4+1)*104 + c] = bfr(fmaf(v.y, s, o));
    Atl[(p4+2)*104 + c] = bfr(fmaf(v.z, s, o));
    Atl[(p4+3)*104 + c] = bfr(fmaf(v.w, s, o));
  }
  __syncthreads();
  int w = tid >> 6, lane = tid & 63, ml = lane & 15, q = lane >> 4;
  int row = w & 3, nh = w >> 2;   // nh in 0..3
  const unsigned short* arow = Atl + (row*16 + ml)*104;
  bf16x8 av[3];
  #pragma unroll
  for(int ks = 0; ks < 3; ++ks) av[ks] = *(const bf16x8*)(arow + ks*32 + q*8);
  f32x4 z = {0.f,0.f,0.f,0.f};
  for(int g = nh; g < 18; g += 4){       // 18 N-groups of 16, striped over 4 wave-columns
    f32x4 acc = z;
    #pragma unroll
    for(int ks = 0; ks < 3; ++ks){
      bf16x8 bv = *(const bf16x8*)(wT + (g*16 + ml)*96 + ks*32 + q*8);
      acc = MFMA16(av[ks], bv, acc);
    }
    int nfb = g*16;
    int t = nfb/96, head = (nfb%96) >> 4;
    float scale = (t == 0) ? 0.25f : 1.0f;
    unsigned short* dst = (t == 0) ? qo : (t == 1) ? ko : vo;
    float bias = qb[nfb + ml];
    #pragma unroll
    for(int r = 0; r < 4; ++r){
      int pxl = pxl0 + row*16 + q*4 + r;
      dst[(((size_t)(b*NHEADS + head))*NP + pxl)*16 + ml] = bfr((acc[r] + bias)*scale);
    }
  }
}

// ---- FUSED attention + proj + residual + stats: block = (b, x-column), 1024 thr ----
// Phase A: 768 thr = 2 per (head, y), static row-split + shfl_xor(1) combine
// Phase B: 16-wave MFMA proj 64x96x96 from LDS + epilogue
template<int K, int D, int RPB, typename SCT>
__global__ void __launch_bounds__(1024, 4) attnproj_kernel(
    const unsigned short* __restrict__ qb, const unsigned short* __restrict__ kb,
    const unsigned short* __restrict__ vb, const float* __restrict__ rpb,
    const unsigned short* __restrict__ wT, const float* __restrict__ pb,
    const SCT* __restrict__ scx, const float* __restrict__ st,
    const float* __restrict__ m1w, const float* __restrict__ m1b,
    const float* __restrict__ m2w, const float* __restrict__ m2b,
    unsigned short* __restrict__ dst, float* __restrict__ st_out){
  __shared__ __align__(16) char smbuf[26624];    // attout [64][104] bf16 | T [96][68] f32 (aliased)
  __shared__ float rpbl[NHEADS*RPB*RPB];
  __shared__ float ls[32];
  unsigned short* attout = (unsigned short*)smbuf;
  float* T = (float*)smbuf;
  int wid = xswz(blockIdx.x);
  int b = wid >> 6;
  int x = wid & 63;
  int tid = threadIdx.x;
  for(int i = tid; i < NHEADS*RPB*RPB; i += 1024) rpbl[i] = rpb[i];
  __syncthreads();

  constexpr int KLO = (K+1)/2;
  constexpr int KH2 = K - KLO;
  if(tid < 768){
    int half = tid & 1;
    int hy = tid >> 1;
    int head = hy >> 6;
    int y = hy & 63;
    int bh = b*NHEADS + head;
    int gx = (D == 1) ? 0 : (x & (D-1));
    int px = (D == 1) ? x : (x >> 3);
    int Lgx = (64 - gx + D - 1) / D;
    int sx = min(max(px - K/2, 0), Lgx - K);
    int gy = (D == 1) ? 0 : (y & (D-1));
    int py = (D == 1) ? y : (y >> 3);
    int Lgy = (64 - gy + D - 1) / D;
    int sy = min(max(py - K/2, 0), Lgy - K);
    int dxb = sx - px + (K-1);
    int dyb = sy - py + (K-1);
    int pix = x*64 + y;

    float qv[16];
    {
      const uint4* qg = (const uint4*)(qb + ((size_t)bh*NP + pix)*16);
      uint4 qa = qg[0], qb4 = qg[1];
      qv[0]=bflo(qa.x);  qv[1]=bfhi(qa.x);  qv[2]=bflo(qa.y);  qv[3]=bfhi(qa.y);
      qv[4]=bflo(qa.z);  qv[5]=bfhi(qa.z);  qv[6]=bflo(qa.w);  qv[7]=bfhi(qa.w);
      qv[8]=bflo(qb4.x); qv[9]=bfhi(qb4.x); qv[10]=bflo(qb4.y);qv[11]=bfhi(qb4.y);
      qv[12]=bflo(qb4.z);qv[13]=bfhi(qb4.z);qv[14]=bflo(qb4.w);qv[15]=bfhi(qb4.w);
    }
    const unsigned short* kgb = kb + (size_t)bh*NP*16;
    const unsigned short* vgb = vb + (size_t)bh*NP*16;
    const float* br0 = rpbl + (head*RPB + dxb)*RPB + dyb;

    float sc[KLO*K];
    float mx;
    if(half == 0) mx = attn_scores<KLO,K,D>(0,   qv, kgb, gx, sx, gy, sy, br0, RPB, sc);
    else          mx = attn_scores<KH2,K,D>(KLO, qv, kgb, gx, sx, gy, sy, br0, RPB, sc);
    mx = fmaxf(mx, __shfl_xor(mx, 1));
    float sum;
    if(half == 0) sum = attn_expsum<KLO,K>(sc, mx);
    else          sum = attn_expsum<KH2,K>(sc, mx);
    sum += __shfl_xor(sum, 1);
    float rs = 1.0f / sum;
    float acc[16];
    #pragma unroll
    for(int d = 0; d < 16; ++d) acc[d] = 0.f;
    if(half == 0) attn_pv<KLO,K,D>(0,   sc, rs, vgb, gx, sx, gy, sy, acc);
    else          attn_pv<KH2,K,D>(KLO, sc, rs, vgb, gx, sx, gy, sy, acc);
    #pragma unroll
    for(int d = 0; d < 16; ++d) acc[d] += __shfl_xor(acc[d], 1);
    if(half == 0){
      unsigned int ow[8];
      #pragma unroll
      for(int p = 0; p < 8; ++p)
        ow[p] = (unsigned int)bfr(acc[2*p]) | ((unsigned int)bfr(acc[2*p+1]) << 16);
      unsigned short* op = attout + y*104 + head*16;
      *(uint4*)op = make_uint4(ow[0], ow[1], ow[2], ow[3]);
      *(uint4*)(op + 8) = make_uint4(ow[4], ow[5], ow[6], ow[7]);
    }
  }
  __syncthreads();

  // ---- proj GEMM 64x96 (K=96): 16 waves = 4 rowgroups x 4 N-stripes over 6 groups ----
  int w = tid >> 6, lane = tid & 63, ml = lane & 15, q = lane >> 4;
  int row = w & 3, nh = w >> 2;    // nh 0..3
  int gA = nh, gB = nh + 4;
  bool hasB = (gB < 6);
  f32x4 z = {0.f,0.f,0.f,0.f};
  f32x4 accA = z, accB = z;
  {
    const unsigned short* arow = attout + (row*16 + ml)*104;
    bf16x8 av[3];
    #pragma unroll
    for(int ks = 0; ks < 3; ++ks) av[ks] = *(const bf16x8*)(arow + ks*32 + q*8);
    #pragma unroll
    for(int ks = 0; ks < 3; ++ks){
      bf16x8 bvA = *(const bf16x8*)(wT + (gA*16 + ml)*96 + ks*32 + q*8);
      accA = MFMA16(av[ks], bvA, accA);
    }
    if(hasB){
      #pragma unroll
      for(int ks = 0; ks < 3; ++ks){
        bf16x8 bvB = *(const bf16x8*)(wT + (gB*16 + ml)*96 + ks*32 + q*8);
        accB = MFMA16(av[ks], bvB, accB);
      }
    }
  }
  __syncthreads();      // attout reads done; region becomes T
  #pragma unroll
  for(int r = 0; r < 4; ++r)
    T[(gA*16 + ml)*68 + row*16 + q*4 + r] = accA[r];
  if(hasB){
    #pragma unroll
    for(int r = 0; r < 4; ++r)
      T[(gB*16 + ml)*68 + row*16 + q*4 + r] = accB[r];
  }
  __syncthreads();
  // ---- epilogue: residual + rescale/rebias + bf16 store + fp32 stats ----
  int pxl0 = x*64;
  float mean, inv, stdv; get_ms(st, b, mean, inv, stdv);
  float s = 0.f, s2 = 0.f;
  for(int idx = tid; idx < 96*64; idx += 1024){
    int n = idx >> 6, p = idx & 63;
    float rsf = fmaf(m1w[n], stdv, m1b[n]);
    float rbf = fmaf(m2w[n], mean, m2b[n]);
    int ad = (b*CC + n)*NP + pxl0 + p;
    float val = ldf(scx, ad) + (T[n*68 + p] + pb[n])*rsf + rbf;
    dst[ad] = bfr(val);
    s += val; s2 = fmaf(val, val, s2);
  }
  for(int off = 32; off > 0; off >>= 1){ s += __shfl_down(s, off); s2 += __shfl_down(s2, off); }
  if(lane == 0){ ls[w] = s; ls[16+w] = s2; }
  __syncthreads();
  if(tid == 0){
    float a0 = 0.f, a1 = 0.f;
    #pragma unroll
    for(int i = 0; i < 16; ++i){ a0 += ls[i]; a1 += ls[16+i]; }
    atomicAdd(&st_out[b], a0);
    atomicAdd(&st_out[4+b], a1);
  }
}

// ---- FUSED MLP: LN(x2) -> GEMM1(N=384,relu) -> GEMM2(K=384) -> +x1 -> x3 -> pa + gap (1024 thr) ----
__global__ void __launch_bounds__(1024, 4) gemm_mlp_kernel(
    const unsigned short* __restrict__ xin, const float* __restrict__ st,
    const float* __restrict__ lnw, const float* __restrict__ lnb,
    const unsigned short* __restrict__ w1T, const float* __restrict__ b1,
    const unsigned short* __restrict__ w2T, const float* __restrict__ b2,
    const unsigned short* __restrict__ scx,
    const float* __restrict__ m1w, const float* __restrict__ m1b,
    const float* __restrict__ m2w, const float* __restrict__ m2b,
    float* __restrict__ dst,
    const float* __restrict__ bns, const float* __restrict__ pw1t,
    const float* __restrict__ pb1, const float* __restrict__ pw2,
    const float* __restrict__ pb2, float* __restrict__ pa,
    float* __restrict__ gap){
  __shared__ __align__(16) char smbuf[63488];     // Atl 13312 | hidL 50176
  __shared__ float scl[96], ofs[96];
  unsigned short* Atl  = (unsigned short*)smbuf;
  unsigned short* hidL = (unsigned short*)(smbuf + 13312);   // [64][392] bf16
  float* T = (float*)(smbuf + 13312);                        // [96][68] (aliased)
  float* gpart = (float*)smbuf;                              // [8][96] (aliased, pa phase)
  int wid = xswz(blockIdx.x);
  int m_base = wid*64;
  int b = m_base >> 12, pxl0 = m_base & 4095;
  float mean, inv, stdv; get_ms(st, b, mean, inv, stdv);
  int tid = threadIdx.x;
  if(tid < 96){ float s = inv*lnw[tid]; scl[tid] = s; ofs[tid] = lnb[tid] - mean*s; }
  __syncthreads();
  const unsigned short* src = xin + (size_t)b*CC*NP + pxl0;
  for(int idx = tid; idx < 96*16; idx += 1024){
    int c = idx >> 4, p4 = (idx & 15) << 2;
    float4 v; load4(src + (size_t)c*NP + p4, v);
    float s = scl[c], o = ofs[c];
    Atl[(p4+0)*104 + c] = bfr(fmaf(v.x, s, o));
    Atl[(p4+1)*104 + c] = bfr(fmaf(v.y, s, o));
    Atl[(p4+2)*104 + c] = bfr(fmaf(v.z, s, o));
    Atl[(p4+3)*104 + c] = bfr(fmaf(v.w, s, o));
  }
  __syncthreads();
  int w = tid >> 6, lane = tid & 63, ml = lane & 15, q = lane >> 4;
  int row = w & 3, nh = w >> 2;   // nh 0..3
  f32x4 z = {0.f,0.f,0.f,0.f};
  // GEMM1: 64x384, hidden -> LDS (relu); 8 g-groups: g = nh*2 + g0
  {
    const unsigned short* arow = Atl + (row*16 + ml)*104;
    bf16x8 av[3];
    #pragma unroll
    for(int ks = 0; ks < 3; ++ks) av[ks] = *(const bf16x8*)(arow + ks*32 + q*8);
    #pragma unroll
    for(int g0 = 0; g0 < 2; ++g0){
      int g = nh*2 + g0;
      f32x4 acc[3] = {z, z, z};
      #pragma unroll
      for(int ks = 0; ks < 3; ++ks){
        #pragma unroll
        for(int gg = 0; gg < 3; ++gg){
          bf16x8 bv = *(const bf16x8*)(w1T + (g*48 + gg*16 + ml)*96 + ks*32 + q*8);
          acc[gg] = MFMA16(av[ks], bv, acc[gg]);
        }
      }
      #pragma unroll
      for(int gg = 0; gg < 3; ++gg){
        int n = g*48 + gg*16 + ml;
        float bias = b1[n];
        #pragma unroll
        for(int r = 0; r < 4; ++r)
          hidL[(row*16 + q*4 + r)*392 + n] = bfr(fmaxf(acc[gg][r] + bias, 0.f));
      }
    }
  }
  __syncthreads();
  // GEMM2: 64x96, K=384 from LDS hidden; 6 N-groups striped over 4 nh
  int gA = nh, gB = nh + 4;
  bool hasB = (gB < 6);
  f32x4 accA = z, accB = z;
  {
    const unsigned short* arow = hidL + (row*16 + ml)*392;
    for(int ks = 0; ks < 12; ++ks){
      bf16x8 av = *(const bf16x8*)(arow + ks*32 + q*8);
      bf16x8 bvA = *(const bf16x8*)(w2T + (gA*16 + ml)*384 + ks*32 + q*8);
      accA = MFMA16(av, bvA, accA);
      if(hasB){
        bf16x8 bvB = *(const bf16x8*)(w2T + (gB*16 + ml)*384 + ks*32 + q*8);
        accB = MFMA16(av, bvB, accB);
      }
    }
  }
  __syncthreads();      // hidL reads done; region becomes T
  #pragma unroll
  for(int r = 0; r < 4; ++r)
    T[(gA*16 + ml)*68 + row*16 + q*4 + r] = accA[r];
  if(hasB){
    #pragma unroll
    for(int r = 0; r < 4; ++r)
      T[(gB*16 + ml)*68 + row*16 + q*4 + r] = accB[r];
  }
  __syncthreads();
  // epilogue: x3 = sc + (T + b2)*rsf + rbf; store global and back into T for pa phase
  for(int idx = tid; idx < 96*64; idx += 1024){
    int n = idx >> 6, px = idx & 63;
    float rsf = fmaf(m1w[n], stdv, m1b[n]);
    float rbf = fmaf(m2w[n], mean, m2b[n]);
    int ad = (b*CC + n)*NP + pxl0 + px;
    float val = ldf(scx, ad) + (T[n*68 + px] + b2[n])*rsf + rbf;
    dst[ad] = val;
    T[n*68 + px] = val;
  }
  __syncthreads();
  // ---- fused pixel-attention + gap partials (first 512 threads; no inner barriers) ----
  if(tid < 512){
    int pxq = tid >> 3, t = tid & 7;
    float yvv[12], acc[12];
    #pragma unroll
    for(int h = 0; h < 12; ++h) acc[h] = 0.f;
    #pragma unroll 6
    for(int cc = 0; cc < 12; ++cc){
      int c = t*12 + cc;
      float yv = fmaf(T[c*68 + pxq], bns[c], bns[96 + c]);
      yvv[cc] = yv;
      #pragma unroll
      for(int h = 0; h < 12; ++h) acc[h] = fmaf(yv, pw1t[c*12 + h], acc[h]);
    }
    #pragma unroll
    for(int h = 0; h < 12; ++h){
      acc[h] += __shfl_xor(acc[h], 1);
      acc[h] += __shfl_xor(acc[h], 2);
      acc[h] += __shfl_xor(acc[h], 4);
    }
    float s = pb2[0];
    #pragma unroll
    for(int h = 0; h < 12; ++h) s = fmaf(gelu_f(acc[h] + pb1[h]), pw2[h], s);
    float pav = sigmoid_f(s);
    if(t == 0) pa[b*NP + pxl0 + pxq] = pav;
    #pragma unroll 6
    for(int cc = 0; cc < 12; ++cc){
      float g = yvv[cc] * pav;
      g += __shfl_xor(g, 8);  g += __shfl_xor(g, 16); g += __shfl_xor(g, 32);
      if(lane < 8) gpart[w*96 + lane*12 + cc] = g;
    }
  }
  __syncthreads();
  if(tid < 96){
    int c = tid;
    float v = 0.f;
    #pragma unroll
    for(int ww = 0; ww < 8; ++ww) v += gpart[ww*96 + c];
    atomicAdd(&gap[b*96 + c], v * (1.0f/4096.0f));
  }
}

// ---- fused m2a + ca: ca from gap, BN*pa*ca -> GEMM1 -> gelu -> GEMM2 -> +x3 (1024 thr) ----
__global__ void __launch_bounds__(1024, 4) gemm_m2a_kernel(
    const float* __restrict__ x3, const float* __restrict__ bns,
    const float* __restrict__ pa, const float* __restrict__ gap,
    const float* __restrict__ cw1T, const float* __restrict__ cb1,
    const float* __restrict__ cw2T, const float* __restrict__ cb2,
    const unsigned short* __restrict__ w1T, const float* __restrict__ b1,
    const unsigned short* __restrict__ w2T, const float* __restrict__ b2,
    const float* __restrict__ scx, float* __restrict__ outp){
  __shared__ __align__(16) char smbuf[26624];
  __shared__ float scl[96], ofs[96], pal[64];
  __shared__ float gl[96], tl[96];
  unsigned short* Atl = (unsigned short*)smbuf;
  unsigned short* tl2 = (unsigned short*)(smbuf + 13312);
  float* T = (float*)smbuf;
  int wid = xswz(blockIdx.x);
  int m_base = wid*64;
  int b = m_base >> 12, pxl0 = m_base & 4095;
  int tid = threadIdx.x;
  if(tid < 96) gl[tid] = gap[b*96 + tid];
  if(tid >= 128 && tid < 192) pal[tid-128] = pa[m_base + (tid-128)];
  __syncthreads();
  if(tid < 96){
    float a = cb1[tid];
    #pragma unroll 8
    for(int c = 0; c < 96; ++c) a = fmaf(gl[c], cw1T[c*96 + tid], a);
    tl[tid] = gelu_f(a);
  }
  __syncthreads();
  if(tid < 96){
    float a = cb2[tid];
    #pragma unroll 8
    for(int c = 0; c < 96; ++c) a = fmaf(tl[c], cw2T[c*96 + tid], a);
    float cv = sigmoid_f(a);
    scl[tid] = bns[tid]*cv; ofs[tid] = bns[96+tid]*cv;
  }
  __syncthreads();
  const float* src = x3 + (size_t)b*CC*NP + pxl0;
  for(int idx = tid; idx < 96*16; idx += 1024){
    int c = idx >> 4, p4 = (idx & 15) << 2;
    float4 v = *(const float4*)(src + (size_t)c*NP + p4);
    float s = scl[c], o = ofs[c];
    Atl[(p4+0)*104 + c] = bfr(fmaf(v.x, s, o) * pal[p4+0]);
    Atl[(p4+1)*104 + c] = bfr(fmaf(v.y, s, o) * pal[p4+1]);
    Atl[(p4+2)*104 + c] = bfr(fmaf(v.z, s, o) * pal[p4+2]);
    Atl[(p4+3)*104 + c] = bfr(fmaf(v.w, s, o) * pal[p4+3]);
  }
  __syncthreads();
  int w = tid >> 6, lane = tid & 63, ml = lane & 15, q = lane >> 4;
  int row = w & 3, nh = w >> 2;   // nh 0..3
  f32x4 z = {0.f,0.f,0.f,0.f};
  // GEMM1: 6 N-groups striped; write tl2 per-group (separate LDS region)
  {
    const unsigned short* arow = Atl + (row*16 + ml)*104;
    bf16x8 av[3];
    #pragma unroll
    for(int ks = 0; ks < 3; ++ks) av[ks] = *(const bf16x8*)(arow + ks*32 + q*8);
    for(int g = nh; g < 6; g += 4){
      f32x4 acc1 = z;
      #pragma unroll
      for(int ks = 0; ks < 3; ++ks){
        bf16x8 bv = *(const bf16x8*)(w1T + (g*16 + ml)*96 + ks*32 + q*8);
        acc1 = MFMA16(av[ks], bv, acc1);
      }
      float bias = b1[g*16 + ml];
      #pragma unroll
      for(int r = 0; r < 4; ++r)
        tl2[(row*16 + q*4 + r)*104 + g*16 + ml] = bfr(gelu_f(acc1[r] + bias));
    }
  }
  __syncthreads();
  // GEMM2: 6 N-groups striped; hold accs across barrier (T spans Atl+tl2)
  int gA = nh, gB = nh + 4;
  bool hasB = (gB < 6);
  f32x4 accA = z, accB = z;
  {
    const unsigned short* arow = tl2 + (row*16 + ml)*104;
    #pragma unroll
    for(int ks = 0; ks < 3; ++ks){
      bf16x8 av = *(const bf16x8*)(arow + ks*32 + q*8);
      bf16x8 bvA = *(const bf16x8*)(w2T + (gA*16 + ml)*96 + ks*32 + q*8);
      accA = MFMA16(av, bvA, accA);
      if(hasB){
        bf16x8 bvB = *(const bf16x8*)(w2T + (gB*16 + ml)*96 + ks*32 + q*8);
        accB = MFMA16(av, bvB, accB);
      }
    }
  }
  __syncthreads();
  #pragma unroll
  for(int r = 0; r < 4; ++r)
    T[(gA*16 + ml)*68 + row*16 + q*4 + r] = accA[r];
  if(hasB){
    #pragma unroll
    for(int r = 0; r < 4; ++r)
      T[(gB*16 + ml)*68 + row*16 + q*4 + r] = accB[r];
  }
  __syncthreads();
  for(int idx = tid; idx < 96*64; idx += 1024){
    int n = idx >> 6, p = idx & 63;
    int ad = (b*CC + n)*NP + pxl0 + p;
    outp[ad] = scx[ad] + T[n*68 + p] + b2[n];
  }
}

extern "C" void kernel_launch(void* const* d_in, const int* in_sizes, int n_in,
                              void* d_out, int out_size, void* d_ws, size_t ws_size,
                              hipStream_t stream){
  (void)in_sizes; (void)n_in; (void)out_size; (void)ws_size;
  const float* x     = (const float*)d_in[0];
  const float* lnw   = (const float*)d_in[1];
  const float* lnb   = (const float*)d_in[2];
  const float* m1w   = (const float*)d_in[3];
  const float* m1b   = (const float*)d_in[4];
  const float* m2w   = (const float*)d_in[5];
  const float* m2b   = (const float*)d_in[6];
  const float* qkv1w = (const float*)d_in[7];
  const float* qkv1b = (const float*)d_in[8];
  const float* proj1w= (const float*)d_in[9];
  const float* proj1b= (const float*)d_in[10];
  const float* rpb1  = (const float*)d_in[11];
  const float* qkv2w = (const float*)d_in[12];
  const float* qkv2b = (const float*)d_in[13];
  const float* proj2w= (const float*)d_in[14];
  const float* proj2b= (const float*)d_in[15];
  const float* rpb2  = (const float*)d_in[16];
  const float* mw1   = (const float*)d_in[17];
  const float* mb1   = (const float*)d_in[18];
  const float* mw2   = (const float*)d_in[19];
  const float* mb2   = (const float*)d_in[20];
  const float* bng   = (const float*)d_in[21];
  const float* bnb   = (const float*)d_in[22];
  const float* bnm   = (const float*)d_in[23];
  const float* bnv   = (const float*)d_in[24];
  const float* paw1  = (const float*)d_in[25];
  const float* pab1  = (const float*)d_in[26];
  const float* paw2  = (const float*)d_in[27];
  const float* pab2  = (const float*)d_in[28];
  const float* caw1  = (const float*)d_in[29];
  const float* cab1  = (const float*)d_in[30];
  const float* caw2  = (const float*)d_in[31];
  const float* cab2  = (const float*)d_in[32];
  const float* aw1   = (const float*)d_in[33];
  const float* ab1   = (const float*)d_in[34];
  const float* aw2   = (const float*)d_in[35];
  const float* ab2   = (const float*)d_in[36];

  float* ws  = (float*)d_ws;
  float* out = (float*)d_out;
  float* st0 = ws;
  float* st1 = ws + 8;
  float* st2 = ws + 16;
  unsigned short* q     = (unsigned short*)(ws + WS_Q);
  unsigned short* k     = (unsigned short*)(ws + WS_K);
  unsigned short* v     = (unsigned short*)(ws + WS_V);
  unsigned short* x1b   = (unsigned short*)(ws + WS_X1);
  unsigned short* x2b   = (unsigned short*)(ws + WS_X2);
  float* x3  = ws + WS_X3;
  float* pab = ws + WS_PA;
  float* gpb = ws + WS_GAP;
  float* bns = ws + WBNS;

  hipMemsetAsync(d_ws, 0, 64*sizeof(float), stream);
  prep_stats_kernel<<<1111, 256, 0, stream>>>(x, st0, qkv1w, qkv2w, proj1w, proj2w,
                                              mw1, mw2, aw1, aw2, paw1,
                                              bng, bnb, bnm, bnv, caw1, caw2, ws);

  // stage 1: attn k=7 d=1 (fused attn+proj)
  gemm_qkv_kernel<float><<<256, 1024, 0, stream>>>(x, st0, lnw, lnb,
      (unsigned short*)(ws+WQKV1), qkv1b, q, k, v);
  attnproj_kernel<7,1,13,float><<<256, 1024, 0, stream>>>(q, k, v, rpb1,
      (unsigned short*)(ws+WPROJ1), proj1b, x, st0, m1w, m1b, m2w, m2b, x1b, st1);

  // stage 2: attn k=5 d=8 (fused attn+proj)
  gemm_qkv_kernel<unsigned short><<<256, 1024, 0, stream>>>(x1b, st1, lnw, lnb,
      (unsigned short*)(ws+WQKV2), qkv2b, q, k, v);
  attnproj_kernel<5,8,9,unsigned short><<<256, 1024, 0, stream>>>(q, k, v, rpb2,
      (unsigned short*)(ws+WPROJ2), proj2b, x1b, st1, m1w, m1b, m2w, m2b, x2b, st2);

  // stage 3: fused MLP (sc = x1) + pa + gap
  gemm_mlp_kernel<<<256, 1024, 0, stream>>>(x2b, st2, lnw, lnb,
      (unsigned short*)(ws+WMLP1), mb1, (unsigned short*)(ws+WMLP2), mb2,
      x1b, m1w, m1b, m2w, m2b, x3,
      bns, ws + WPA1T, pab1, paw2, pab2, pab, gpb);

  // stage 4: fused (ca + m2a)
  gemm_m2a_kernel<<<256, 1024, 0, stream>>>(x3, bns, pab, gpb,
                                            ws + WCA1T, cab1, ws + WCA2T, cab2,
                                            (unsigned short*)(ws+WM2A1), ab1,
                                            (unsigned short*)(ws+WM2A2), ab2, x3, out);
}

// Round 12
// 247.687 us; speedup vs baseline: 1.9051x; 1.3163x over previous
//
#include <hip/hip_runtime.h>
#include <math.h>

#define CC 96
#define NP 4096
#define NHEADS 6
#define NELEMF 393216.0f
#define EPSF 1e-5f

typedef __attribute__((ext_vector_type(8))) short bf16x8;
typedef __attribute__((ext_vector_type(4))) float f32x4;
#define MFMA16(a,b,c) __builtin_amdgcn_mfma_f32_16x16x32_bf16(a,b,c,0,0,0)

// ---- workspace layout (float offsets) ----
#define WQKV1  64
#define WQKV2  (WQKV1+13824)
#define WPROJ1 (WQKV2+13824)
#define WPROJ2 (WPROJ1+4608)
#define WMLP1  (WPROJ2+4608)
#define WMLP2  (WMLP1+18432)
#define WM2A1  (WMLP2+18432)
#define WM2A2  (WM2A1+4608)
#define WPA1T  (WM2A2+4608)
#define WBNS   (WPA1T+1152)
#define WCA1T  (WBNS+192)
#define WCA2T  (WCA1T+9216)
#define WS_Q   870784
#define WS_K   (WS_Q+786432)
#define WS_V   (WS_K+786432)
#define WS_X1  (WS_V+786432+786432)
#define WS_X2  (WS_X1+1572864)
#define WS_X3  (WS_X2+1572864)
#define WS_PA  (WS_X3+1572864)
#define WS_GAP (WS_PA+16384)

__device__ __forceinline__ float gelu_f(float x){
  return 0.5f * x * (1.0f + erff(x * 0.7071067811865476f));
}
__device__ __forceinline__ float sigmoid_f(float x){
  return 1.0f / (1.0f + __expf(-x));
}
__device__ __forceinline__ unsigned short bfr(float f){
  unsigned int u = __float_as_uint(f);
  u += 0x7fffu + ((u >> 16) & 1u);
  return (unsigned short)(u >> 16);
}
__device__ __forceinline__ float bflo16(unsigned short u){ return __uint_as_float(((unsigned int)u) << 16); }
__device__ __forceinline__ float bflo(unsigned int u){ return __uint_as_float(u << 16); }
__device__ __forceinline__ float bfhi(unsigned int u){ return __uint_as_float(u & 0xffff0000u); }
__device__ __forceinline__ void get_ms(const float* st, int b, float& mean, float& inv, float& stdv){
  float s = st[b], s2 = st[4+b];
  mean = s * (1.0f/NELEMF);
  float var = fmaxf(s2 * (1.0f/NELEMF) - mean*mean, 0.0f);
  stdv = sqrtf(var + EPSF);
  inv = 1.0f / stdv;
}
__device__ __forceinline__ float ldf(const float* p, int i){ return p[i]; }
__device__ __forceinline__ float ldf(const unsigned short* p, int i){ return bflo16(p[i]); }
__device__ __forceinline__ void load4(const float* p, float4& v){ v = *(const float4*)p; }
__device__ __forceinline__ void load4(const unsigned short* p, float4& v){
  ushort4 u = *(const ushort4*)p;
  v.x = bflo16(u.x); v.y = bflo16(u.y); v.z = bflo16(u.z); v.w = bflo16(u.w);
}
__device__ __forceinline__ float dotg(const float* qv, const uint4* p){
  uint4 a = p[0], b = p[1];
  float s;
  s  = qv[0]*bflo(a.x);            s = fmaf(qv[1],  bfhi(a.x), s);
  s = fmaf(qv[2],  bflo(a.y), s);  s = fmaf(qv[3],  bfhi(a.y), s);
  s = fmaf(qv[4],  bflo(a.z), s);  s = fmaf(qv[5],  bfhi(a.z), s);
  s = fmaf(qv[6],  bflo(a.w), s);  s = fmaf(qv[7],  bfhi(a.w), s);
  s = fmaf(qv[8],  bflo(b.x), s);  s = fmaf(qv[9],  bfhi(b.x), s);
  s = fmaf(qv[10], bflo(b.y), s);  s = fmaf(qv[11], bfhi(b.y), s);
  s = fmaf(qv[12], bflo(b.z), s);  s = fmaf(qv[13], bfhi(b.z), s);
  s = fmaf(qv[14], bflo(b.w), s);  s = fmaf(qv[15], bfhi(b.w), s);
  return s;
}
__device__ __forceinline__ void pvg(float w, const uint4* p, float* acc){
  uint4 a = p[0], b = p[1];
  acc[0]  = fmaf(w, bflo(a.x), acc[0]);  acc[1]  = fmaf(w, bfhi(a.x), acc[1]);
  acc[2]  = fmaf(w, bflo(a.y), acc[2]);  acc[3]  = fmaf(w, bfhi(a.y), acc[3]);
  acc[4]  = fmaf(w, bflo(a.z), acc[4]);  acc[5]  = fmaf(w, bfhi(a.z), acc[5]);
  acc[6]  = fmaf(w, bflo(a.w), acc[6]);  acc[7]  = fmaf(w, bfhi(a.w), acc[7]);
  acc[8]  = fmaf(w, bflo(b.x), acc[8]);  acc[9]  = fmaf(w, bfhi(b.x), acc[9]);
  acc[10] = fmaf(w, bflo(b.y), acc[10]); acc[11] = fmaf(w, bfhi(b.y), acc[11]);
  acc[12] = fmaf(w, bflo(b.z), acc[12]); acc[13] = fmaf(w, bfhi(b.z), acc[13]);
  acc[14] = fmaf(w, bflo(b.w), acc[14]); acc[15] = fmaf(w, bfhi(b.w), acc[15]);
}
// XCD-aware bijective swizzle for 256-block grids (8 XCDs x 32 consecutive tiles)
__device__ __forceinline__ int xswz(int bid){ return ((bid & 7) << 5) | (bid >> 3); }

// ---- combined: stats(x) for blocks <384, weight prep + gap zero for blocks >=384 ----
__global__ void prep_stats_kernel(const float* __restrict__ x, float* __restrict__ st,
                             const float* __restrict__ q1, const float* __restrict__ q2,
                             const float* __restrict__ p1, const float* __restrict__ p2,
                             const float* __restrict__ w1, const float* __restrict__ w2,
                             const float* __restrict__ a1, const float* __restrict__ a2,
                             const float* __restrict__ pw1,
                             const float* __restrict__ bg, const float* __restrict__ bb,
                             const float* __restrict__ bm, const float* __restrict__ bv,
                             const float* __restrict__ cw1, const float* __restrict__ cw2,
                             float* __restrict__ ws){
  if(blockIdx.x < 384){
    int b = blockIdx.x / CC, c = blockIdx.x % CC;
    const float4* p4 = (const float4*)(x + (size_t)(b*CC + c)*NP);
    float s = 0.f, s2 = 0.f;
    for(int i = threadIdx.x; i < 1024; i += 256){
      float4 v = p4[i];
      s += v.x + v.y + v.z + v.w;
      s2 = fmaf(v.x, v.x, fmaf(v.y, v.y, fmaf(v.z, v.z, fmaf(v.w, v.w, s2))));
    }
    for(int off = 32; off > 0; off >>= 1){ s += __shfl_down(s, off); s2 += __shfl_down(s2, off); }
    __shared__ float ls[8];
    int wid = threadIdx.x >> 6;
    if((threadIdx.x & 63) == 0){ ls[wid] = s; ls[4+wid] = s2; }
    __syncthreads();
    if(threadIdx.x == 0){
      atomicAdd(&st[b],   ls[0]+ls[1]+ls[2]+ls[3]);
      atomicAdd(&st[4+b], ls[4]+ls[5]+ls[6]+ls[7]);
    }
    return;
  }
  int gid = (blockIdx.x - 384)*256 + threadIdx.x;
  if(gid < 27648){ int n = gid/96, c = gid%96; ((unsigned short*)(ws+WQKV1))[gid] = bfr(q1[c*288+n]); }
  else if(gid < 55296){ int g = gid-27648; int n = g/96, c = g%96; ((unsigned short*)(ws+WQKV2))[g] = bfr(q2[c*288+n]); }
  else if(gid < 64512){ int g = gid-55296; int n = g/96, c = g%96; ((unsigned short*)(ws+WPROJ1))[g] = bfr(p1[c*96+n]); }
  else if(gid < 73728){ int g = gid-64512; int n = g/96, c = g%96; ((unsigned short*)(ws+WPROJ2))[g] = bfr(p2[c*96+n]); }
  else if(gid < 110592){ int g = gid-73728; ((unsigned short*)(ws+WMLP1))[g] = bfr(w1[g]); }
  else if(gid < 147456){ int g = gid-110592; ((unsigned short*)(ws+WMLP2))[g] = bfr(w2[g]); }
  else if(gid < 156672){ int g = gid-147456; ((unsigned short*)(ws+WM2A1))[g] = bfr(a1[g]); }
  else if(gid < 165888){ int g = gid-156672; ((unsigned short*)(ws+WM2A2))[g] = bfr(a2[g]); }
  else if(gid < 167040){ int g = gid-165888; int c = g/12, h = g%12; ws[WPA1T + g] = pw1[h*96+c]; }
  else if(gid < 167136){ int c = gid-167040;
    float sc = rsqrtf(bv[c] + EPSF) * bg[c];
    ws[WBNS + c] = sc;
    ws[WBNS + 96 + c] = bb[c] - bm[c]*sc;
  }
  else if(gid < 167520){ ws[WS_GAP + (gid-167136)] = 0.f; }
  else if(gid < 176736){ int g = gid-167520; int o = g/96, c = g%96; ws[WCA1T + c*96 + o] = cw1[g]; }
  else if(gid < 185952){ int g = gid-176736; int o = g/96, c = g%96; ws[WCA2T + c*96 + o] = cw2[g]; }
}

// ---- fused LN + QKV GEMM: M=64-px block, 512 thr (8 waves = 4 rows x 2 N-halves) ----
template<typename AT>
__global__ void __launch_bounds__(512) gemm_qkv_kernel(
    const AT* __restrict__ xin, const float* __restrict__ st,
    const float* __restrict__ lnw, const float* __restrict__ lnb,
    const unsigned short* __restrict__ wT, const float* __restrict__ qb,
    unsigned short* __restrict__ qo, unsigned short* __restrict__ ko, unsigned short* __restrict__ vo){
  __shared__ unsigned short Atl[64*104];
  __shared__ float scl[96], ofs[96];
  int m_base = xswz(blockIdx.x)*64;
  int b = m_base >> 12, pxl0 = m_base & 4095;
  float mean, inv, stdv; get_ms(st, b, mean, inv, stdv);
  int tid = threadIdx.x;
  if(tid < 96){ float s = inv*lnw[tid]; scl[tid] = s; ofs[tid] = lnb[tid] - mean*s; }
  __syncthreads();
  const AT* src = xin + (size_t)b*CC*NP + pxl0;
  for(int idx = tid; idx < 96*16; idx += 512){
    int c = idx >> 4, p4 = (idx & 15) << 2;
    float4 v; load4(src + (size_t)c*NP + p4, v);
    float s = scl[c], o = ofs[c];
    Atl[(p4+0)*104 + c] = bfr(fmaf(v.x, s, o));
    Atl[(p4+1)*104 + c] = bfr(fmaf(v.y, s, o));
    Atl[(p4+2)*104 + c] = bfr(fmaf(v.z, s, o));
    Atl[(p4+3)*104 + c] = bfr(fmaf(v.w, s, o));
  }
  __syncthreads();
  int w = tid >> 6, lane = tid & 63, ml = lane & 15, q = lane >> 4;
  int row = w & 3, nh = w >> 2;
  const unsigned short* arow = Atl + (row*16 + ml)*104;
  bf16x8 av[3];
  #pragma unroll
  for(int ks = 0; ks < 3; ++ks) av[ks] = *(const bf16x8*)(arow + ks*32 + q*8);
  f32x4 z = {0.f,0.f,0.f,0.f};
  #pragma unroll
  for(int g0 = 0; g0 < 3; ++g0){
    int g = nh*3 + g0;
    f32x4 acc[3] = {z, z, z};
    #pragma unroll
    for(int ks = 0; ks < 3; ++ks){
      #pragma unroll
      for(int gg = 0; gg < 3; ++gg){
        bf16x8 bv = *(const bf16x8*)(wT + (g*48 + gg*16 + ml)*96 + ks*32 + q*8);
        acc[gg] = MFMA16(av[ks], bv, acc[gg]);
      }
    }
    #pragma unroll
    for(int gg = 0; gg < 3; ++gg){
      int nfb = g*48 + gg*16;
      int t = nfb/96, head = (nfb%96) >> 4;
      float scale = (t == 0) ? 0.25f : 1.0f;
      unsigned short* dst = (t == 0) ? qo : (t == 1) ? ko : vo;
      float bias = qb[nfb + ml];
      #pragma unroll
      for(int r = 0; r < 4; ++r){
        int pxl = pxl0 + row*16 + q*4 + r;
        dst[(((size_t)(b*NHEADS + head))*NP + pxl)*16 + ml] = bfr((acc[gg][r] + bias)*scale);
      }
    }
  }
}

// ---- FUSED attention + proj + residual + stats: block = (b, x-column), 512 thr ----
// Phase A: 384 thr = (head, y), k/v read direct from L2, out -> LDS
// Phase B: 8-wave MFMA proj 64x96x96 from LDS + epilogue
template<int K, int D, int RPB, typename SCT>
__global__ void __launch_bounds__(512) attnproj_kernel(
    const unsigned short* __restrict__ qb, const unsigned short* __restrict__ kb,
    const unsigned short* __restrict__ vb, const float* __restrict__ rpb,
    const unsigned short* __restrict__ wT, const float* __restrict__ pb,
    const SCT* __restrict__ scx, const float* __restrict__ st,
    const float* __restrict__ m1w, const float* __restrict__ m1b,
    const float* __restrict__ m2w, const float* __restrict__ m2b,
    unsigned short* __restrict__ dst, float* __restrict__ st_out){
  __shared__ __align__(16) char smbuf[26624];    // attout [64][104] bf16 | T [96][68] f32 (aliased)
  __shared__ float rpbl[NHEADS*RPB*RPB];
  __shared__ float ls[16];
  unsigned short* attout = (unsigned short*)smbuf;
  float* T = (float*)smbuf;
  int wid = xswz(blockIdx.x);
  int b = wid >> 6;
  int x = wid & 63;
  int tid = threadIdx.x;
  for(int i = tid; i < NHEADS*RPB*RPB; i += 512) rpbl[i] = rpb[i];
  __syncthreads();

  if(tid < 384){
    int head = tid >> 6;
    int y = tid & 63;
    int bh = b*NHEADS + head;
    int gx = (D == 1) ? 0 : (x & (D-1));
    int px = (D == 1) ? x : (x >> 3);
    int Lgx = (64 - gx + D - 1) / D;
    int sx = min(max(px - K/2, 0), Lgx - K);
    int gy = (D == 1) ? 0 : (y & (D-1));
    int py = (D == 1) ? y : (y >> 3);
    int Lgy = (64 - gy + D - 1) / D;
    int sy = min(max(py - K/2, 0), Lgy - K);
    int dxb = sx - px + (K-1);
    int dyb = sy - py + (K-1);
    int pix = x*64 + y;

    float qv[16];
    {
      const uint4* qg = (const uint4*)(qb + ((size_t)bh*NP + pix)*16);
      uint4 qa = qg[0], qb4 = qg[1];
      qv[0]=bflo(qa.x);  qv[1]=bfhi(qa.x);  qv[2]=bflo(qa.y);  qv[3]=bfhi(qa.y);
      qv[4]=bflo(qa.z);  qv[5]=bfhi(qa.z);  qv[6]=bflo(qa.w);  qv[7]=bfhi(qa.w);
      qv[8]=bflo(qb4.x); qv[9]=bfhi(qb4.x); qv[10]=bflo(qb4.y);qv[11]=bfhi(qb4.y);
      qv[12]=bflo(qb4.z);qv[13]=bfhi(qb4.z);qv[14]=bflo(qb4.w);qv[15]=bfhi(qb4.w);
    }
    const unsigned short* kgb = kb + (size_t)bh*NP*16;
    const unsigned short* vgb = vb + (size_t)bh*NP*16;

    float sc[K*K];
    #pragma unroll
    for(int i = 0; i < K; ++i){
      int colx = gx + D*(sx + i);
      const unsigned short* kcol = kgb + (size_t)colx*64*16;
      const float* br = rpbl + (head*RPB + (i + dxb))*RPB + dyb;
      #pragma unroll
      for(int j = 0; j < K; ++j){
        int wwy = gy + D*(sy + j);
        sc[i*K + j] = dotg(qv, (const uint4*)(kcol + wwy*16)) + br[j];
      }
    }
    float mx = -1e30f;
    #pragma unroll
    for(int n = 0; n < K*K; ++n) mx = fmaxf(mx, sc[n]);
    float sum = 0.f;
    #pragma unroll
    for(int n = 0; n < K*K; ++n){ float e = __expf(sc[n] - mx); sc[n] = e; sum += e; }
    float rs = 1.0f / sum;
    float acc[16];
    #pragma unroll
    for(int d = 0; d < 16; ++d) acc[d] = 0.f;
    #pragma unroll
    for(int i = 0; i < K; ++i){
      int colx = gx + D*(sx + i);
      const unsigned short* vcol = vgb + (size_t)colx*64*16;
      #pragma unroll
      for(int j = 0; j < K; ++j){
        int wwy = gy + D*(sy + j);
        pvg(sc[i*K + j] * rs, (const uint4*)(vcol + wwy*16), acc);
      }
    }
    unsigned int ow[8];
    #pragma unroll
    for(int p = 0; p < 8; ++p)
      ow[p] = (unsigned int)bfr(acc[2*p]) | ((unsigned int)bfr(acc[2*p+1]) << 16);
    unsigned short* op = attout + y*104 + head*16;
    *(uint4*)op = make_uint4(ow[0], ow[1], ow[2], ow[3]);
    *(uint4*)(op + 8) = make_uint4(ow[4], ow[5], ow[6], ow[7]);
  }
  __syncthreads();

  // ---- proj GEMM 64x96 (K=96): 8 waves = 4 rowgroups x 2 N-halves(48) ----
  int w = tid >> 6, lane = tid & 63, ml = lane & 15, q = lane >> 4;
  int row = w & 3, nh = w >> 2;
  f32x4 z = {0.f,0.f,0.f,0.f};
  f32x4 acc[3] = {z, z, z};
  {
    const unsigned short* arow = attout + (row*16 + ml)*104;
    #pragma unroll
    for(int ks = 0; ks < 3; ++ks){
      bf16x8 av = *(const bf16x8*)(arow + ks*32 + q*8);
      #pragma unroll
      for(int g0 = 0; g0 < 3; ++g0){
        int g = nh*3 + g0;
        bf16x8 bv = *(const bf16x8*)(wT + (g*16 + ml)*96 + ks*32 + q*8);
        acc[g0] = MFMA16(av, bv, acc[g0]);
      }
    }
  }
  __syncthreads();      // attout reads done; region becomes T
  #pragma unroll
  for(int g0 = 0; g0 < 3; ++g0){
    int g = nh*3 + g0;
    #pragma unroll
    for(int r = 0; r < 4; ++r)
      T[(g*16 + ml)*68 + row*16 + q*4 + r] = acc[g0][r];
  }
  __syncthreads();
  // ---- epilogue: residual + rescale/rebias + bf16 store + fp32 stats for next LN ----
  int pxl0 = x*64;
  float mean, inv, stdv; get_ms(st, b, mean, inv, stdv);
  float s = 0.f, s2 = 0.f;
  for(int idx = tid; idx < 96*64; idx += 512){
    int n = idx >> 6, p = idx & 63;
    float rsf = fmaf(m1w[n], stdv, m1b[n]);
    float rbf = fmaf(m2w[n], mean, m2b[n]);
    int ad = (b*CC + n)*NP + pxl0 + p;
    float val = ldf(scx, ad) + (T[n*68 + p] + pb[n])*rsf + rbf;
    dst[ad] = bfr(val);
    s += val; s2 = fmaf(val, val, s2);
  }
  for(int off = 32; off > 0; off >>= 1){ s += __shfl_down(s, off); s2 += __shfl_down(s2, off); }
  if(lane == 0){ ls[w] = s; ls[8+w] = s2; }
  __syncthreads();
  if(tid == 0){
    float a0 = 0.f, a1 = 0.f;
    #pragma unroll
    for(int i = 0; i < 8; ++i){ a0 += ls[i]; a1 += ls[8+i]; }
    atomicAdd(&st_out[b], a0);
    atomicAdd(&st_out[4+b], a1);
  }
}

// ---- FUSED MLP: LN(x2) -> GEMM1(N=384,relu) -> GEMM2(K=384) -> +x1 -> x3 -> pa + gap (512 thr) ----
__global__ void __launch_bounds__(512) gemm_mlp_kernel(
    const unsigned short* __restrict__ xin, const float* __restrict__ st,
    const float* __restrict__ lnw, const float* __restrict__ lnb,
    const unsigned short* __restrict__ w1T, const float* __restrict__ b1,
    const unsigned short* __restrict__ w2T, const float* __restrict__ b2,
    const unsigned short* __restrict__ scx,
    const float* __restrict__ m1w, const float* __restrict__ m1b,
    const float* __restrict__ m2w, const float* __restrict__ m2b,
    float* __restrict__ dst,
    const float* __restrict__ bns, const float* __restrict__ pw1t,
    const float* __restrict__ pb1, const float* __restrict__ pw2,
    const float* __restrict__ pb2, float* __restrict__ pa,
    float* __restrict__ gap){
  __shared__ __align__(16) char smbuf[63488];     // Atl 13312 | hidL 50176
  __shared__ float scl[96], ofs[96];
  unsigned short* Atl  = (unsigned short*)smbuf;
  unsigned short* hidL = (unsigned short*)(smbuf + 13312);   // [64][392] bf16
  float* T = (float*)(smbuf + 13312);                        // aliases hidL (epilogue) [96][68]
  float* gpart = (float*)smbuf;                              // aliases Atl (pa phase) [8][96]
  int m_base = xswz(blockIdx.x)*64;
  int b = m_base >> 12, pxl0 = m_base & 4095;
  float mean, inv, stdv; get_ms(st, b, mean, inv, stdv);
  int tid = threadIdx.x;
  if(tid < 96){ float s = inv*lnw[tid]; scl[tid] = s; ofs[tid] = lnb[tid] - mean*s; }
  __syncthreads();
  const unsigned short* src = xin + (size_t)b*CC*NP + pxl0;
  for(int idx = tid; idx < 96*16; idx += 512){
    int c = idx >> 4, p4 = (idx & 15) << 2;
    float4 v; load4(src + (size_t)c*NP + p4, v);
    float s = scl[c], o = ofs[c];
    Atl[(p4+0)*104 + c] = bfr(fmaf(v.x, s, o));
    Atl[(p4+1)*104 + c] = bfr(fmaf(v.y, s, o));
    Atl[(p4+2)*104 + c] = bfr(fmaf(v.z, s, o));
    Atl[(p4+3)*104 + c] = bfr(fmaf(v.w, s, o));
  }
  __syncthreads();
  int w = tid >> 6, lane = tid & 63, ml = lane & 15, q = lane >> 4;
  int row = w & 3, nh = w >> 2;
  f32x4 z = {0.f,0.f,0.f,0.f};
  // GEMM1: 64x384, hidden -> LDS (relu); 8 N-groups split over 2 wave-halves
  {
    const unsigned short* arow = Atl + (row*16 + ml)*104;
    bf16x8 av[3];
    #pragma unroll
    for(int ks = 0; ks < 3; ++ks) av[ks] = *(const bf16x8*)(arow + ks*32 + q*8);
    #pragma unroll
    for(int g0 = 0; g0 < 4; ++g0){
      int g = nh*4 + g0;
      f32x4 acc[3] = {z, z, z};
      #pragma unroll
      for(int ks = 0; ks < 3; ++ks){
        #pragma unroll
        for(int gg = 0; gg < 3; ++gg){
          bf16x8 bv = *(const bf16x8*)(w1T + (g*48 + gg*16 + ml)*96 + ks*32 + q*8);
          acc[gg] = MFMA16(av[ks], bv, acc[gg]);
        }
      }
      #pragma unroll
      for(int gg = 0; gg < 3; ++gg){
        int n = g*48 + gg*16 + ml;
        float bias = b1[n];
        #pragma unroll
        for(int r = 0; r < 4; ++r)
          hidL[(row*16 + q*4 + r)*392 + n] = bfr(fmaxf(acc[gg][r] + bias, 0.f));
      }
    }
  }
  __syncthreads();
  // GEMM2: 64x96, K=384 from LDS hidden; 6 N-groups split over 2 wave-halves
  f32x4 acc2[3] = {z, z, z};
  {
    const unsigned short* arow = hidL + (row*16 + ml)*392;
    #pragma unroll
    for(int ks = 0; ks < 12; ++ks){
      bf16x8 av = *(const bf16x8*)(arow + ks*32 + q*8);
      #pragma unroll
      for(int g0 = 0; g0 < 3; ++g0){
        int g = nh*3 + g0;
        bf16x8 bv = *(const bf16x8*)(w2T + (g*16 + ml)*384 + ks*32 + q*8);
        acc2[g0] = MFMA16(av, bv, acc2[g0]);
      }
    }
  }
  __syncthreads();      // hidL reads done; region becomes T
  #pragma unroll
  for(int g0 = 0; g0 < 3; ++g0){
    int g = nh*3 + g0;
    #pragma unroll
    for(int r = 0; r < 4; ++r)
      T[(g*16 + ml)*68 + row*16 + q*4 + r] = acc2[g0][r];
  }
  __syncthreads();
  // epilogue: x3 = sc + (T + b2)*rsf + rbf; store global and back into T for pa phase
  for(int idx = tid; idx < 96*64; idx += 512){
    int n = idx >> 6, px = idx & 63;
    float rsf = fmaf(m1w[n], stdv, m1b[n]);
    float rbf = fmaf(m2w[n], mean, m2b[n]);
    int ad = (b*CC + n)*NP + pxl0 + px;
    float val = ldf(scx, ad) + (T[n*68 + px] + b2[n])*rsf + rbf;
    dst[ad] = val;
    T[n*68 + px] = val;
  }
  __syncthreads();
  // ---- fused pixel-attention + gap partials over this 64-px tile ----
  int pxq = tid >> 3, t = tid & 7;
  float yvv[12], acc[12];
  #pragma unroll
  for(int h = 0; h < 12; ++h) acc[h] = 0.f;
  #pragma unroll 6
  for(int cc = 0; cc < 12; ++cc){
    int c = t*12 + cc;
    float yv = fmaf(T[c*68 + pxq], bns[c], bns[96 + c]);
    yvv[cc] = yv;
    #pragma unroll
    for(int h = 0; h < 12; ++h) acc[h] = fmaf(yv, pw1t[c*12 + h], acc[h]);
  }
  #pragma unroll
  for(int h = 0; h < 12; ++h){
    acc[h] += __shfl_xor(acc[h], 1);
    acc[h] += __shfl_xor(acc[h], 2);
    acc[h] += __shfl_xor(acc[h], 4);
  }
  float s = pb2[0];
  #pragma unroll
  for(int h = 0; h < 12; ++h) s = fmaf(gelu_f(acc[h] + pb1[h]), pw2[h], s);
  float pav = sigmoid_f(s);
  if(t == 0) pa[b*NP + pxl0 + pxq] = pav;
  #pragma unroll 6
  for(int cc = 0; cc < 12; ++cc){
    float g = yvv[cc] * pav;
    g += __shfl_xor(g, 8);  g += __shfl_xor(g, 16); g += __shfl_xor(g, 32);
    if(lane < 8) gpart[w*96 + lane*12 + cc] = g;
  }
  __syncthreads();
  if(tid < 96){
    int c = tid;
    float v = 0.f;
    #pragma unroll
    for(int ww = 0; ww < 8; ++ww) v += gpart[ww*96 + c];
    atomicAdd(&gap[b*96 + c], v * (1.0f/4096.0f));
  }
}

// ---- fused m2a + ca: compute ca from gap, then BN*pa*ca -> GEMM1 -> gelu -> GEMM2 -> +x3 (512 thr) ----
__global__ void __launch_bounds__(512) gemm_m2a_kernel(
    const float* __restrict__ x3, const float* __restrict__ bns,
    const float* __restrict__ pa, const float* __restrict__ gap,
    const float* __restrict__ cw1T, const float* __restrict__ cb1,
    const float* __restrict__ cw2T, const float* __restrict__ cb2,
    const unsigned short* __restrict__ w1T, const float* __restrict__ b1,
    const unsigned short* __restrict__ w2T, const float* __restrict__ b2,
    const float* __restrict__ scx, float* __restrict__ outp){
  __shared__ __align__(16) char smbuf[26624];
  __shared__ float scl[96], ofs[96], pal[64];
  __shared__ float gl[96], tl[96];
  unsigned short* Atl = (unsigned short*)smbuf;
  unsigned short* tl2 = (unsigned short*)(smbuf + 13312);
  float* T = (float*)smbuf;
  int m_base = xswz(blockIdx.x)*64;
  int b = m_base >> 12, pxl0 = m_base & 4095;
  int tid = threadIdx.x;
  // --- ca for this batch, from gap (transposed ca weights -> coalesced) ---
  if(tid < 96) gl[tid] = gap[b*96 + tid];
  if(tid >= 128 && tid < 192) pal[tid-128] = pa[b*NP + pxl0 + (tid-128)];
  __syncthreads();
  if(tid < 96){
    float a = cb1[tid];
    #pragma unroll 8
    for(int c = 0; c < 96; ++c) a = fmaf(gl[c], cw1T[c*96 + tid], a);
    tl[tid] = gelu_f(a);
  }
  __syncthreads();
  if(tid < 96){
    float a = cb2[tid];
    #pragma unroll 8
    for(int c = 0; c < 96; ++c) a = fmaf(tl[c], cw2T[c*96 + tid], a);
    float cv = sigmoid_f(a);
    scl[tid] = bns[tid]*cv; ofs[tid] = bns[96+tid]*cv;
  }
  __syncthreads();
  const float* src = x3 + (size_t)b*CC*NP + pxl0;
  for(int idx = tid; idx < 96*16; idx += 512){
    int c = idx >> 4, p4 = (idx & 15) << 2;
    float4 v = *(const float4*)(src + (size_t)c*NP + p4);
    float s = scl[c], o = ofs[c];
    Atl[(p4+0)*104 + c] = bfr(fmaf(v.x, s, o) * pal[p4+0]);
    Atl[(p4+1)*104 + c] = bfr(fmaf(v.y, s, o) * pal[p4+1]);
    Atl[(p4+2)*104 + c] = bfr(fmaf(v.z, s, o) * pal[p4+2]);
    Atl[(p4+3)*104 + c] = bfr(fmaf(v.w, s, o) * pal[p4+3]);
  }
  __syncthreads();
  int w = tid >> 6, lane = tid & 63, ml = lane & 15, q = lane >> 4;
  int row = w & 3, nh = w >> 2;
  f32x4 z = {0.f,0.f,0.f,0.f};
  f32x4 acc1[3] = {z, z, z};
  {
    const unsigned short* arow = Atl + (row*16 + ml)*104;
    #pragma unroll
    for(int ks = 0; ks < 3; ++ks){
      bf16x8 av = *(const bf16x8*)(arow + ks*32 + q*8);
      #pragma unroll
      for(int g0 = 0; g0 < 3; ++g0){
        int g = nh*3 + g0;
        bf16x8 bv = *(const bf16x8*)(w1T + (g*16 + ml)*96 + ks*32 + q*8);
        acc1[g0] = MFMA16(av, bv, acc1[g0]);
      }
    }
  }
  #pragma unroll
  for(int g0 = 0; g0 < 3; ++g0){
    int g = nh*3 + g0;
    float bias = b1[g*16 + ml];
    #pragma unroll
    for(int r = 0; r < 4; ++r)
      tl2[(row*16 + q*4 + r)*104 + g*16 + ml] = bfr(gelu_f(acc1[g0][r] + bias));
  }
  __syncthreads();
  f32x4 acc2[3] = {z, z, z};
  {
    const unsigned short* arow = tl2 + (row*16 + ml)*104;
    #pragma unroll
    for(int ks = 0; ks < 3; ++ks){
      bf16x8 av = *(const bf16x8*)(arow + ks*32 + q*8);
      #pragma unroll
      for(int g0 = 0; g0 < 3; ++g0){
        int g = nh*3 + g0;
        bf16x8 bv = *(const bf16x8*)(w2T + (g*16 + ml)*96 + ks*32 + q*8);
        acc2[g0] = MFMA16(av, bv, acc2[g0]);
      }
    }
  }
  __syncthreads();
  #pragma unroll
  for(int g0 = 0; g0 < 3; ++g0){
    int g = nh*3 + g0;
    #pragma unroll
    for(int r = 0; r < 4; ++r)
      T[(g*16 + ml)*68 + row*16 + q*4 + r] = acc2[g0][r];
  }
  __syncthreads();
  for(int idx = tid; idx < 96*64; idx += 512){
    int n = idx >> 6, p = idx & 63;
    int ad = (b*CC + n)*NP + pxl0 + p;
    outp[ad] = scx[ad] + T[n*68 + p] + b2[n];
  }
}

extern "C" void kernel_launch(void* const* d_in, const int* in_sizes, int n_in,
                              void* d_out, int out_size, void* d_ws, size_t ws_size,
                              hipStream_t stream){
  (void)in_sizes; (void)n_in; (void)out_size; (void)ws_size;
  const float* x     = (const float*)d_in[0];
  const float* lnw   = (const float*)d_in[1];
  const float* lnb   = (const float*)d_in[2];
  const float* m1w   = (const float*)d_in[3];
  const float* m1b   = (const float*)d_in[4];
  const float* m2w   = (const float*)d_in[5];
  const float* m2b   = (const float*)d_in[6];
  const float* qkv1w = (const float*)d_in[7];
  const float* qkv1b = (const float*)d_in[8];
  const float* proj1w= (const float*)d_in[9];
  const float* proj1b= (const float*)d_in[10];
  const float* rpb1  = (const float*)d_in[11];
  const float* qkv2w = (const float*)d_in[12];
  const float* qkv2b = (const float*)d_in[13];
  const float* proj2w= (const float*)d_in[14];
  const float* proj2b= (const float*)d_in[15];
  const float* rpb2  = (const float*)d_in[16];
  const float* mw1   = (const float*)d_in[17];
  const float* mb1   = (const float*)d_in[18];
  const float* mw2   = (const float*)d_in[19];
  const float* mb2   = (const float*)d_in[20];
  const float* bng   = (const float*)d_in[21];
  const float* bnb   = (const float*)d_in[22];
  const float* bnm   = (const float*)d_in[23];
  const float* bnv   = (const float*)d_in[24];
  const float* paw1  = (const float*)d_in[25];
  const float* pab1  = (const float*)d_in[26];
  const float* paw2  = (const float*)d_in[27];
  const float* pab2  = (const float*)d_in[28];
  const float* caw1  = (const float*)d_in[29];
  const float* cab1  = (const float*)d_in[30];
  const float* caw2  = (const float*)d_in[31];
  const float* cab2  = (const float*)d_in[32];
  const float* aw1   = (const float*)d_in[33];
  const float* ab1   = (const float*)d_in[34];
  const float* aw2   = (const float*)d_in[35];
  const float* ab2   = (const float*)d_in[36];

  float* ws  = (float*)d_ws;
  float* out = (float*)d_out;
  float* st0 = ws;
  float* st1 = ws + 8;
  float* st2 = ws + 16;
  unsigned short* q     = (unsigned short*)(ws + WS_Q);
  unsigned short* k     = (unsigned short*)(ws + WS_K);
  unsigned short* v     = (unsigned short*)(ws + WS_V);
  unsigned short* x1b   = (unsigned short*)(ws + WS_X1);
  unsigned short* x2b   = (unsigned short*)(ws + WS_X2);
  float* x3  = ws + WS_X3;
  float* pab = ws + WS_PA;
  float* gpb = ws + WS_GAP;
  float* bns = ws + WBNS;

  hipMemsetAsync(d_ws, 0, 64*sizeof(float), stream);
  prep_stats_kernel<<<1111, 256, 0, stream>>>(x, st0, qkv1w, qkv2w, proj1w, proj2w,
                                              mw1, mw2, aw1, aw2, paw1,
                                              bng, bnb, bnm, bnv, caw1, caw2, ws);

  // stage 1: attn k=7 d=1 (fused attn+proj, column-per-block)
  gemm_qkv_kernel<float><<<256, 512, 0, stream>>>(x, st0, lnw, lnb,
      (unsigned short*)(ws+WQKV1), qkv1b, q, k, v);
  attnproj_kernel<7,1,13,float><<<256, 512, 0, stream>>>(q, k, v, rpb1,
      (unsigned short*)(ws+WPROJ1), proj1b, x, st0, m1w, m1b, m2w, m2b, x1b, st1);

  // stage 2: attn k=5 d=8 (fused attn+proj)
  gemm_qkv_kernel<unsigned short><<<256, 512, 0, stream>>>(x1b, st1, lnw, lnb,
      (unsigned short*)(ws+WQKV2), qkv2b, q, k, v);
  attnproj_kernel<5,8,9,unsigned short><<<256, 512, 0, stream>>>(q, k, v, rpb2,
      (unsigned short*)(ws+WPROJ2), proj2b, x1b, st1, m1w, m1b, m2w, m2b, x2b, st2);

  // stage 3: fused MLP (sc = x1) + pa + gap
  gemm_mlp_kernel<<<256, 512, 0, stream>>>(x2b, st2, lnw, lnb,
      (unsigned short*)(ws+WMLP1), mb1, (unsigned short*)(ws+WMLP2), mb2,
      x1b, m1w, m1b, m2w, m2b, x3,
      bns, ws + WPA1T, pab1, paw2, pab2, pab, gpb);

  // stage 4: fused (ca + m2a)
  gemm_m2a_kernel<<<256, 512, 0, stream>>>(x3, bns, pab, gpb,
                                           ws + WCA1T, cab1, ws + WCA2T, cab2,
                                           (unsigned short*)(ws+WM2A1), ab1,
                                           (unsigned short*)(ws+WM2A2), ab2, x3, out);
}